// Round 5
// baseline (1257.419 us; speedup 1.0000x reference)
//
#include <hip/hip_runtime.h>
#include <hip/hip_bf16.h>

typedef __bf16 bf16_t;
typedef bf16_t bf16x8 __attribute__((ext_vector_type(8)));
typedef bf16_t bf16x4 __attribute__((ext_vector_type(4)));
typedef float f32x4 __attribute__((ext_vector_type(4)));

#define DD 256
#define MM 64
#define RR 12

__device__ __forceinline__ float gelu_fast(float x) {
    // tanh-approx gelu via exp identity: tanh(u) = sign(u)*(1-e^{-2|u|})/(1+e^{-2|u|})
    float u = x * (0.7978845608f + 0.0356774081f * x * x);
    float t = __expf(-2.f * fabsf(u));
    float th = (1.f - t) / (1.f + t);
    th = copysignf(th, u);
    return 0.5f * x * (1.f + th);
}

__device__ __forceinline__ bf16x8 zero8() {
    bf16x8 z;
#pragma unroll
    for (int i = 0; i < 8; ++i) z[i] = (bf16_t)0.f;
    return z;
}

// ---------- weight prep: fp32 [K][C] -> bf16 transposed [C][K], batched over blockIdx.y ----------
__global__ void cvt_transpose_kernel(const float* __restrict__ src, bf16_t* __restrict__ dst,
                                     int K, int C) {
    int m = blockIdx.y;
    const float* s = src + (size_t)m * K * C;
    bf16_t* d = dst + (size_t)m * K * C;
    int idx = blockIdx.x * 256 + threadIdx.x;
    if (idx < K * C) {
        int k = idx / C, c = idx - k * C;
        d[c * K + k] = (bf16_t)s[idx];
    }
}

// ---------- streamed-B fc stage: acc += lds_in(32x256) @ B(256 x 32cols-of-wave) ----------
__device__ __forceinline__ void fc_stage256(const bf16_t (*ldsin)[264], const bf16_t* __restrict__ BT,
                                            int l15, int lhi, f32x4 acc[2][2]) {
    bf16x8 bb[3][2];
#pragma unroll
    for (int p = 0; p < 2; ++p)
#pragma unroll
        for (int nf = 0; nf < 2; ++nf)
            bb[p][nf] = *(const bf16x8*)(BT + (size_t)(nf * 16 + l15) * 256 + p * 32 + lhi * 8);
#pragma unroll
    for (int ks = 0; ks < 8; ++ks) {
        if (ks + 2 < 8) {
#pragma unroll
            for (int nf = 0; nf < 2; ++nf)
                bb[(ks + 2) % 3][nf] =
                    *(const bf16x8*)(BT + (size_t)(nf * 16 + l15) * 256 + (ks + 2) * 32 + lhi * 8);
        }
        bf16x8 a0 = *(const bf16x8*)&ldsin[l15][ks * 32 + lhi * 8];
        bf16x8 a1 = *(const bf16x8*)&ldsin[16 + l15][ks * 32 + lhi * 8];
#pragma unroll
        for (int nf = 0; nf < 2; ++nf) {
            acc[0][nf] = __builtin_amdgcn_mfma_f32_16x16x32_bf16(a0, bb[ks % 3][nf], acc[0][nf], 0, 0, 0);
            acc[1][nf] = __builtin_amdgcn_mfma_f32_16x16x32_bf16(a1, bb[ks % 3][nf], acc[1][nf], 0, 0, 0);
        }
    }
}

// ---------- streamed-B Wv stage: 16 cols of v for one wave ----------
__device__ __forceinline__ void wv_stage(const bf16_t (*ldsin)[264], const bf16_t* __restrict__ BT,
                                         int l15, int lhi, f32x4 av[2]) {
    bf16x8 bb[3];
#pragma unroll
    for (int p = 0; p < 2; ++p)
        bb[p] = *(const bf16x8*)(BT + (size_t)l15 * 256 + p * 32 + lhi * 8);
#pragma unroll
    for (int ks = 0; ks < 8; ++ks) {
        if (ks + 2 < 8)
            bb[(ks + 2) % 3] = *(const bf16x8*)(BT + (size_t)l15 * 256 + (ks + 2) * 32 + lhi * 8);
        bf16x8 a0 = *(const bf16x8*)&ldsin[l15][ks * 32 + lhi * 8];
        bf16x8 a1 = *(const bf16x8*)&ldsin[16 + l15][ks * 32 + lhi * 8];
        av[0] = __builtin_amdgcn_mfma_f32_16x16x32_bf16(a0, bb[ks % 3], av[0], 0, 0, 0);
        av[1] = __builtin_amdgcn_mfma_f32_16x16x32_bf16(a1, bb[ks % 3], av[1], 0, 0, 0);
    }
}

// ---------- fused interaction block + fused Wv for next layer ----------
__global__ __launch_bounds__(512, 4) void block_fused(
    const bf16_t* __restrict__ aggb, float* __restrict__ x, const bf16_t* __restrict__ woutt,
    const bf16_t* __restrict__ fc1t, const bf16_t* __restrict__ fc2t,
    const float* __restrict__ b1, const float* __restrict__ b2,
    const bf16_t* __restrict__ wvt_n, bf16_t* __restrict__ vb, int M) {
    __shared__ bf16_t lds1[32][264];
    __shared__ bf16_t lds2[32][264];
    const int t = threadIdx.x, wave = t >> 6, lane = t & 63;
    const int l15 = lane & 15, lhi = lane >> 4;
    const int cb = wave * 32;
    const int STRIDE = gridDim.x * 32;
    const bf16x8 z8 = zero8();
    float bias1[2], bias2[2];
#pragma unroll
    for (int nf = 0; nf < 2; ++nf) {
        bias1[nf] = b1[cb + nf * 16 + l15];
        bias2[nf] = b2[cb + nf * 16 + l15];
    }

    float pfx[2][2][4];
    bf16x8 pfa[2][2];
    auto PREFETCH = [&](int r0) {
        const int rr0 = r0 + l15, rr1 = r0 + 16 + l15;
#pragma unroll
        for (int ks = 0; ks < 2; ++ks) {
            pfa[0][ks] = (rr0 < M) ? *(const bf16x8*)(aggb + (size_t)rr0 * 64 + ks * 32 + lhi * 8) : z8;
            pfa[1][ks] = (rr1 < M) ? *(const bf16x8*)(aggb + (size_t)rr1 * 64 + ks * 32 + lhi * 8) : z8;
        }
#pragma unroll
        for (int mf = 0; mf < 2; ++mf)
#pragma unroll
            for (int nf = 0; nf < 2; ++nf)
#pragma unroll
                for (int r = 0; r < 4; ++r) {
                    int row = r0 + mf * 16 + lhi * 4 + r;
                    pfx[mf][nf][r] = (row < M) ? x[(size_t)row * 256 + cb + nf * 16 + l15] : 0.f;
                }
    };

    PREFETCH(blockIdx.x * 32);
    for (int row0 = blockIdx.x * 32; row0 < M; row0 += STRIDE) {
        __syncthreads();  // protect lds1 from previous tile's readers
        // ---- phase A: h = agg@Wout + x ----
        bf16x8 bwf[2][2];
#pragma unroll
        for (int ks = 0; ks < 2; ++ks)
#pragma unroll
            for (int nf = 0; nf < 2; ++nf)
                bwf[ks][nf] =
                    *(const bf16x8*)(woutt + (size_t)(cb + nf * 16 + l15) * 64 + ks * 32 + lhi * 8);
        f32x4 h[2][2];
#pragma unroll
        for (int mf = 0; mf < 2; ++mf)
#pragma unroll
            for (int nf = 0; nf < 2; ++nf) h[mf][nf] = (f32x4){0.f, 0.f, 0.f, 0.f};
#pragma unroll
        for (int ks = 0; ks < 2; ++ks)
#pragma unroll
            for (int nf = 0; nf < 2; ++nf) {
                h[0][nf] = __builtin_amdgcn_mfma_f32_16x16x32_bf16(pfa[0][ks], bwf[ks][nf], h[0][nf], 0, 0, 0);
                h[1][nf] = __builtin_amdgcn_mfma_f32_16x16x32_bf16(pfa[1][ks], bwf[ks][nf], h[1][nf], 0, 0, 0);
            }
#pragma unroll
        for (int mf = 0; mf < 2; ++mf)
#pragma unroll
            for (int nf = 0; nf < 2; ++nf) {
                int col = cb + nf * 16 + l15;
#pragma unroll
                for (int r = 0; r < 4; ++r) {
                    float hv = h[mf][nf][r] + pfx[mf][nf][r];
                    h[mf][nf][r] = hv;
                    lds1[mf * 16 + lhi * 4 + r][col] = (bf16_t)hv;
                }
            }
        __syncthreads();  // B1
        if (row0 + STRIDE < M) PREFETCH(row0 + STRIDE);  // hide under fc1+fc2
        // ---- fc1 ----
        f32x4 acc[2][2];
#pragma unroll
        for (int mf = 0; mf < 2; ++mf)
#pragma unroll
            for (int nf = 0; nf < 2; ++nf) acc[mf][nf] = (f32x4){0.f, 0.f, 0.f, 0.f};
        fc_stage256(lds1, fc1t + (size_t)cb * 256, l15, lhi, acc);
#pragma unroll
        for (int mf = 0; mf < 2; ++mf)
#pragma unroll
            for (int nf = 0; nf < 2; ++nf) {
                int col = cb + nf * 16 + l15;
#pragma unroll
                for (int r = 0; r < 4; ++r)
                    lds2[mf * 16 + lhi * 4 + r][col] = (bf16_t)gelu_fast(acc[mf][nf][r] + bias1[nf]);
            }
        __syncthreads();  // B2
        // ---- fc2 + residual epilogue ----
#pragma unroll
        for (int mf = 0; mf < 2; ++mf)
#pragma unroll
            for (int nf = 0; nf < 2; ++nf) acc[mf][nf] = (f32x4){0.f, 0.f, 0.f, 0.f};
        fc_stage256(lds2, fc2t + (size_t)cb * 256, l15, lhi, acc);
#pragma unroll
        for (int mf = 0; mf < 2; ++mf)
#pragma unroll
            for (int nf = 0; nf < 2; ++nf) {
                int col = cb + nf * 16 + l15;
#pragma unroll
                for (int r = 0; r < 4; ++r) {
                    int lrow = mf * 16 + lhi * 4 + r;
                    int row = row0 + lrow;
                    float o = h[mf][nf][r] + gelu_fast(acc[mf][nf][r] + bias2[nf]);
                    if (row < M) x[(size_t)row * 256 + col] = o;
                    lds1[lrow][col] = (bf16_t)o;
                }
            }
        if (wvt_n) {
            __syncthreads();  // B3: xnew staged in lds1
            if (wave < 4) {
                f32x4 av[2];
                av[0] = (f32x4){0.f, 0.f, 0.f, 0.f};
                av[1] = (f32x4){0.f, 0.f, 0.f, 0.f};
                wv_stage(lds1, wvt_n + (size_t)(wave * 16) * 256, l15, lhi, av);
#pragma unroll
                for (int mf = 0; mf < 2; ++mf)
#pragma unroll
                    for (int r = 0; r < 4; ++r) {
                        int row = row0 + mf * 16 + lhi * 4 + r;
                        if (row < M) vb[(size_t)row * 64 + wave * 16 + l15] = (bf16_t)av[mf][r];
                    }
            }
        }
    }
}

// ---------- fused init: embed -> fc0.1 -> fc0.2 -> Wv0 ----------
__global__ __launch_bounds__(512, 4) void fc0_fused(
    const int* __restrict__ z, const float* __restrict__ table, const float* __restrict__ embW,
    const float* __restrict__ embb, const bf16_t* __restrict__ fc1t,
    const bf16_t* __restrict__ fc2t, const float* __restrict__ b1, const float* __restrict__ b2,
    const bf16_t* __restrict__ wvt0, bf16_t* __restrict__ vb, float* __restrict__ x, int M) {
    __shared__ bf16_t lds1[32][264];
    __shared__ bf16_t lds2[32][264];
    const int t = threadIdx.x, wave = t >> 6, lane = t & 63;
    const int l15 = lane & 15, lhi = lane >> 4;
    const int cb = wave * 32;
    const int erow = t >> 4, ecol0 = (t & 15) * 16;
    const int STRIDE = gridDim.x * 32;
    float bias1[2], bias2[2];
#pragma unroll
    for (int nf = 0; nf < 2; ++nf) {
        bias1[nf] = b1[cb + nf * 16 + l15];
        bias2[nf] = b2[cb + nf * 16 + l15];
    }

    for (int row0 = blockIdx.x * 32; row0 < M; row0 += STRIDE) {
        __syncthreads();
        // ---- embed into lds1 ----
        int grow = row0 + erow;
        if (grow < M) {
            int zi = z[grow];
            float tr[5];
#pragma unroll
            for (int hh = 0; hh < 5; ++hh) tr[hh] = table[zi * 5 + hh];
#pragma unroll
            for (int c = 0; c < 16; ++c) {
                int col = ecol0 + c;
                float a = embb[col];
#pragma unroll
                for (int hh = 0; hh < 5; ++hh) a += tr[hh] * embW[hh * 256 + col];
                lds1[erow][col] = (bf16_t)a;
            }
        } else {
#pragma unroll
            for (int c = 0; c < 16; ++c) lds1[erow][ecol0 + c] = (bf16_t)0.f;
        }
        __syncthreads();
        // ---- fc0.1 ----
        f32x4 acc[2][2];
#pragma unroll
        for (int mf = 0; mf < 2; ++mf)
#pragma unroll
            for (int nf = 0; nf < 2; ++nf) acc[mf][nf] = (f32x4){0.f, 0.f, 0.f, 0.f};
        fc_stage256(lds1, fc1t + (size_t)cb * 256, l15, lhi, acc);
#pragma unroll
        for (int mf = 0; mf < 2; ++mf)
#pragma unroll
            for (int nf = 0; nf < 2; ++nf) {
                int col = cb + nf * 16 + l15;
#pragma unroll
                for (int r = 0; r < 4; ++r)
                    lds2[mf * 16 + lhi * 4 + r][col] = (bf16_t)gelu_fast(acc[mf][nf][r] + bias1[nf]);
            }
        __syncthreads();
        // ---- fc0.2 ----
#pragma unroll
        for (int mf = 0; mf < 2; ++mf)
#pragma unroll
            for (int nf = 0; nf < 2; ++nf) acc[mf][nf] = (f32x4){0.f, 0.f, 0.f, 0.f};
        fc_stage256(lds2, fc2t + (size_t)cb * 256, l15, lhi, acc);
#pragma unroll
        for (int mf = 0; mf < 2; ++mf)
#pragma unroll
            for (int nf = 0; nf < 2; ++nf) {
                int col = cb + nf * 16 + l15;
#pragma unroll
                for (int r = 0; r < 4; ++r) {
                    int lrow = mf * 16 + lhi * 4 + r;
                    int row = row0 + lrow;
                    float o = gelu_fast(acc[mf][nf][r] + bias2[nf]);
                    if (row < M) x[(size_t)row * 256 + col] = o;
                    lds1[lrow][col] = (bf16_t)o;
                }
            }
        __syncthreads();  // x0 staged in lds1
        if (wave < 4) {
            f32x4 av[2];
            av[0] = (f32x4){0.f, 0.f, 0.f, 0.f};
            av[1] = (f32x4){0.f, 0.f, 0.f, 0.f};
            wv_stage(lds1, wvt0 + (size_t)(wave * 16) * 256, l15, lhi, av);
#pragma unroll
            for (int mf = 0; mf < 2; ++mf)
#pragma unroll
                for (int r = 0; r < 4; ++r) {
                    int row = row0 + mf * 16 + lhi * 4 + r;
                    if (row < M) vb[(size_t)row * 64 + wave * 16 + l15] = (bf16_t)av[mf][r];
                }
        }
    }
}

// ---------- CSR build ----------
__global__ void count_kernel(const int* __restrict__ ei, int* __restrict__ deg, int E) {
    int e = blockIdx.x * 256 + threadIdx.x;
    if (e < E) atomicAdd(&deg[ei[e]], 1);
}

__global__ void scan_local(const int* __restrict__ deg, int* __restrict__ rs,
                           int* __restrict__ bsum, int N) {
    __shared__ int sd[1024];
    int t = threadIdx.x, i = blockIdx.x * 1024 + t;
    int val = (i < N) ? deg[i] : 0;
    sd[t] = val;
    __syncthreads();
    for (int off = 1; off < 1024; off <<= 1) {
        int tv = (t >= off) ? sd[t - off] : 0;
        __syncthreads();
        sd[t] += tv;
        __syncthreads();
    }
    if (i < N) rs[i] = sd[t] - val;
    if (t == 1023) bsum[blockIdx.x] = sd[1023];
}

__global__ void scan_bsums(int* __restrict__ bsum, int nb) {
    if (threadIdx.x == 0) {
        int run = 0;
        for (int b = 0; b < nb; ++b) {
            int v = bsum[b];
            bsum[b] = run;
            run += v;
        }
        bsum[nb] = run;
    }
}

__global__ void scan_add(int* __restrict__ rs, const int* __restrict__ bsum, int N) {
    int i = blockIdx.x * 1024 + threadIdx.x;
    if (i < N) rs[i] += bsum[blockIdx.x];
    if (i == 0) rs[N] = bsum[gridDim.x];
}

__global__ void fill_kernel(const int* __restrict__ ei, const int* __restrict__ row_start,
                            int* __restrict__ cursor, int* __restrict__ csr_eid,
                            int* __restrict__ csr_j, int E) {
    int e = blockIdx.x * 256 + threadIdx.x;
    if (e < E) {
        int i = ei[e];
        int p = atomicAdd(&cursor[i], 1);
        int o = row_start[i] + p;
        csr_eid[o] = e;
        csr_j[o] = ei[E + e];
    }
}

// ---------- rbf in CSR order (bf16, rows padded to 16 elems / 32B, pad zeroed) ----------
__global__ void rbf_csr_kernel(const int* __restrict__ csr_eid, const int* __restrict__ ei,
                               const float* __restrict__ pos, const float* __restrict__ freqs,
                               bf16_t* __restrict__ rbf_csr, int E) {
    int idx = blockIdx.x * 256 + threadIdx.x;
    if (idx >= E) return;
    int e = csr_eid[idx];
    int i = ei[e], j = ei[E + e];
    float dx = pos[i * 3 + 0] - pos[j * 3 + 0];
    float dy = pos[i * 3 + 1] - pos[j * 3 + 1];
    float dz = pos[i * 3 + 2] - pos[j * 3 + 2];
    float dist = sqrtf(dx * dx + dy * dy + dz * dz + 1e-12f);
    float x = dist * 0.2f;
    float x4 = (x * x) * (x * x);
    float env = 1.0f / x + x4 * (-21.0f + x * (35.0f - 15.0f * x));
    bf16x8 lo, hi;
#pragma unroll
    for (int r = 0; r < 8; ++r) lo[r] = (bf16_t)(env * sinf(freqs[r] * x));
#pragma unroll
    for (int r = 0; r < 4; ++r) hi[r] = (bf16_t)(env * sinf(freqs[8 + r] * x));
#pragma unroll
    for (int r = 4; r < 8; ++r) hi[r] = (bf16_t)0.f;
    bf16_t* dst = rbf_csr + (size_t)idx * 16;
    *(bf16x8*)dst = lo;
    *(bf16x8*)(dst + 8) = hi;
}

// ---------- message gather: MFMA-based gate (rbf@Wrbf) + coalesced v gather ----------
// wave = 1 node; 16-edge groups; gate via 4x mfma_16x16x32 (K zero-padded beyond 12).
// dim permutation: MFMA nf covers dim = l15*4 + nf so v loads are contiguous bf16x4.
__global__ __launch_bounds__(256) void msg_kernel(const int* __restrict__ row_start,
                                                  const int* __restrict__ csr_j,
                                                  const bf16_t* __restrict__ rbf_csr,
                                                  const bf16_t* __restrict__ v,
                                                  const float* __restrict__ Wrbf,
                                                  bf16_t* __restrict__ agg, int N, int E) {
    const int wave = threadIdx.x >> 6, lane = threadIdx.x & 63;
    const int l15 = lane & 15, lhi = lane >> 4;
    const int nd = blockIdx.x * 4 + wave;
    if (nd >= N) return;
    bf16x8 wrb[4];
#pragma unroll
    for (int nf = 0; nf < 4; ++nf) {
#pragma unroll
        for (int j = 0; j < 8; ++j) {
            int k = lhi * 8 + j;
            wrb[nf][j] = (k < 12) ? (bf16_t)Wrbf[k * 64 + l15 * 4 + nf] : (bf16_t)0.f;
        }
    }
    const int s = row_start[nd], e = row_start[nd + 1];
    float acc[4] = {0.f, 0.f, 0.f, 0.f};
    const bf16x8 z8 = zero8();
    for (int g0 = s; g0 < e; g0 += 16) {
        int ea = g0 + l15;
        bf16x8 af = (lhi < 2 && ea < e) ? *(const bf16x8*)(rbf_csr + (size_t)ea * 16 + lhi * 8) : z8;
        f32x4 gacc[4];
#pragma unroll
        for (int nf = 0; nf < 4; ++nf)
            gacc[nf] = __builtin_amdgcn_mfma_f32_16x16x32_bf16(af, wrb[nf],
                                                               (f32x4){0.f, 0.f, 0.f, 0.f}, 0, 0, 0);
#pragma unroll
        for (int r = 0; r < 4; ++r) {
            int er = g0 + lhi * 4 + r;
            int jj = csr_j[er < E ? er : E - 1];
            bf16x4 vj = *(const bf16x4*)(v + (size_t)jj * 64 + l15 * 4);
#pragma unroll
            for (int nf = 0; nf < 4; ++nf) acc[nf] += gacc[nf][r] * (float)vj[nf];
        }
    }
#pragma unroll
    for (int nf = 0; nf < 4; ++nf) {
        acc[nf] += __shfl_xor(acc[nf], 16, 64);
        acc[nf] += __shfl_xor(acc[nf], 32, 64);
    }
    if (lhi == 0) {
        bf16x4 o;
#pragma unroll
        for (int nf = 0; nf < 4; ++nf) o[nf] = (bf16_t)acc[nf];
        *(bf16x4*)(agg + (size_t)nd * 64 + l15 * 4) = o;
    }
}

extern "C" void kernel_launch(void* const* d_in, const int* in_sizes, int n_in, void* d_out,
                              int out_size, void* d_ws, size_t ws_size, hipStream_t stream) {
    const int* z = (const int*)d_in[0];
    const float* pos = (const float*)d_in[1];
    const int* ei = (const int*)d_in[4];
    const float* emb_table = (const float*)d_in[5];
    const float* emb_W = (const float*)d_in[6];
    const float* emb_b = (const float*)d_in[7];
    const float* freqs = (const float*)d_in[8];
    const float* fc0_W = (const float*)d_in[9];
    const float* fc0_b = (const float*)d_in[10];
    const float* conv_Wv = (const float*)d_in[11];
    const float* conv_Wrbf = (const float*)d_in[12];
    const float* conv_Wout = (const float*)d_in[13];
    const float* fc_W = (const float*)d_in[14];
    const float* fc_b = (const float*)d_in[15];
    float* x = (float*)d_out;

    const int N = in_sizes[0];
    const int E = in_sizes[4] / 2;

    // ---- workspace carve ----
    char* wsp = (char*)d_ws;
    auto alloc = [&](size_t bytes) {
        void* p = (void*)wsp;
        wsp += (bytes + 255) & ~(size_t)255;
        return p;
    };
    bf16_t* vb = (bf16_t*)alloc((size_t)N * MM * 2);
    bf16_t* aggb = (bf16_t*)alloc((size_t)N * MM * 2);
    bf16_t* rbf_csr = (bf16_t*)alloc((size_t)E * 16 * 2);
    int* deg = (int*)alloc((size_t)N * 4);
    int* cursor = (int*)alloc((size_t)N * 4);
    int* row_start = (int*)alloc((size_t)(N + 1) * 4);
    int* bsum = (int*)alloc((size_t)256 * 4);
    int* csr_eid = (int*)alloc((size_t)E * 4);
    int* csr_j = (int*)alloc((size_t)E * 4);
    bf16_t* wbf = (bf16_t*)alloc((size_t)786432 * 2);
    bf16_t* fc0t = wbf;              // 2 x [256][256]
    bf16_t* fct = wbf + 2 * 65536;   // 8 x [256][256]
    bf16_t* wvt = wbf + 10 * 65536;  // 4 x [64 cols][256 k]
    bf16_t* wott = wvt + 4 * 16384;  // 4 x [256 cols][64 k]

    // ---- weight prep ----
    cvt_transpose_kernel<<<dim3(256, 2), 256, 0, stream>>>(fc0_W, fc0t, 256, 256);
    cvt_transpose_kernel<<<dim3(256, 8), 256, 0, stream>>>(fc_W, fct, 256, 256);
    cvt_transpose_kernel<<<dim3(64, 4), 256, 0, stream>>>(conv_Wv, wvt, 256, 64);
    cvt_transpose_kernel<<<dim3(64, 4), 256, 0, stream>>>(conv_Wout, wott, 64, 256);

    // ---- CSR by destination, rbf in CSR order ----
    hipMemsetAsync(deg, 0, (size_t)N * 4, stream);
    hipMemsetAsync(cursor, 0, (size_t)N * 4, stream);
    count_kernel<<<(E + 255) / 256, 256, 0, stream>>>(ei, deg, E);
    const int nb = (N + 1023) / 1024;
    scan_local<<<nb, 1024, 0, stream>>>(deg, row_start, bsum, N);
    scan_bsums<<<1, 64, 0, stream>>>(bsum, nb);
    scan_add<<<nb, 1024, 0, stream>>>(row_start, bsum, N);
    fill_kernel<<<(E + 255) / 256, 256, 0, stream>>>(ei, row_start, cursor, csr_eid, csr_j, E);
    rbf_csr_kernel<<<(E + 255) / 256, 256, 0, stream>>>(csr_eid, ei, pos, freqs, rbf_csr, E);

    // ---- init: embed + fc0 + Wv0 fused ----
    const int GF = 512;
    fc0_fused<<<GF, 512, 0, stream>>>(z, emb_table, emb_W, emb_b, fc0t, fc0t + 65536, fc0_b,
                                      fc0_b + 256, wvt, vb, x, N);

    // ---- interaction blocks ----
    for (int n = 0; n < 4; ++n) {
        msg_kernel<<<(N + 3) / 4, 256, 0, stream>>>(row_start, csr_j, rbf_csr, vb,
                                                    conv_Wrbf + n * RR * MM, aggb, N, E);
        block_fused<<<GF, 512, 0, stream>>>(aggb, x, wott + n * 16384, fct + (n * 2) * 65536,
                                            fct + (n * 2 + 1) * 65536, fc_b + n * 2 * 256,
                                            fc_b + (n * 2 + 1) * 256,
                                            (n < 3) ? (wvt + (n + 1) * 16384) : (const bf16_t*)nullptr,
                                            vb, N);
    }
}

// Round 6
// 1050.235 us; speedup vs baseline: 1.1973x; 1.1973x over previous
//
#include <hip/hip_runtime.h>
#include <hip/hip_bf16.h>

typedef __bf16 bf16_t;
typedef bf16_t bf16x8 __attribute__((ext_vector_type(8)));
typedef bf16_t bf16x4 __attribute__((ext_vector_type(4)));
typedef float f32x4 __attribute__((ext_vector_type(4)));

#define DD 256
#define MM 64
#define RR 12

__device__ __forceinline__ float gelu_fast(float x) {
    // tanh-approx gelu via exp identity: tanh(u) = sign(u)*(1-e^{-2|u|})/(1+e^{-2|u|})
    float u = x * (0.7978845608f + 0.0356774081f * x * x);
    float t = __expf(-2.f * fabsf(u));
    float th = (1.f - t) / (1.f + t);
    th = copysignf(th, u);
    return 0.5f * x * (1.f + th);
}

__device__ __forceinline__ bf16x8 zero8() {
    bf16x8 z;
#pragma unroll
    for (int i = 0; i < 8; ++i) z[i] = (bf16_t)0.f;
    return z;
}

// ---------- weight prep: fp32 [K][C] -> bf16 transposed [C][K], batched over blockIdx.y ----------
__global__ void cvt_transpose_kernel(const float* __restrict__ src, bf16_t* __restrict__ dst,
                                     int K, int C) {
    int m = blockIdx.y;
    const float* s = src + (size_t)m * K * C;
    bf16_t* d = dst + (size_t)m * K * C;
    int idx = blockIdx.x * 256 + threadIdx.x;
    if (idx < K * C) {
        int k = idx / C, c = idx - k * C;
        d[c * K + k] = (bf16_t)s[idx];
    }
}

// ---------- register-B MFMA GEMM (used for Wv only) ----------
template <int K, int NCOL>
__global__ __launch_bounds__(256, 2) void gemm_rb(const bf16_t* __restrict__ A,
                                                  const bf16_t* __restrict__ Wt,
                                                  bf16_t* __restrict__ Cb, int M) {
    constexpr int NSTEP = K / 32;
    constexpr int NF = NCOL / 64;
    const int t = threadIdx.x;
    const int wave = t >> 6, lane = t & 63;
    const int l15 = lane & 15, lhi = lane >> 4;
    const int colbase = wave * (NCOL / 4);

    bf16x8 bfr[NSTEP][NF];
#pragma unroll
    for (int ks = 0; ks < NSTEP; ++ks)
#pragma unroll
        for (int nf = 0; nf < NF; ++nf)
            bfr[ks][nf] =
                *(const bf16x8*)(Wt + (size_t)(colbase + nf * 16 + l15) * K + ks * 32 + lhi * 8);

    const bf16x8 z8 = zero8();
    for (int row0 = blockIdx.x * 32; row0 < M; row0 += gridDim.x * 32) {
        const int r0 = row0 + l15, r1 = row0 + 16 + l15;
        const bool g0 = r0 < M, g1 = r1 < M;
        const bf16_t* a0p = A + (size_t)r0 * K + lhi * 8;
        const bf16_t* a1p = A + (size_t)r1 * K + lhi * 8;

        f32x4 acc[2][NF];
#pragma unroll
        for (int mf = 0; mf < 2; ++mf)
#pragma unroll
            for (int nf = 0; nf < NF; ++nf) acc[mf][nf] = (f32x4){0.f, 0.f, 0.f, 0.f};

        bf16x8 a0 = g0 ? *(const bf16x8*)a0p : z8;
        bf16x8 a1 = g1 ? *(const bf16x8*)a1p : z8;
#pragma unroll
        for (int ks = 0; ks < NSTEP; ++ks) {
            bf16x8 n0 = z8, n1 = z8;
            if (ks + 1 < NSTEP) {
                n0 = g0 ? *(const bf16x8*)(a0p + (ks + 1) * 32) : z8;
                n1 = g1 ? *(const bf16x8*)(a1p + (ks + 1) * 32) : z8;
            }
#pragma unroll
            for (int nf = 0; nf < NF; ++nf)
                acc[0][nf] = __builtin_amdgcn_mfma_f32_16x16x32_bf16(a0, bfr[ks][nf], acc[0][nf], 0, 0, 0);
#pragma unroll
            for (int nf = 0; nf < NF; ++nf)
                acc[1][nf] = __builtin_amdgcn_mfma_f32_16x16x32_bf16(a1, bfr[ks][nf], acc[1][nf], 0, 0, 0);
            a0 = n0;
            a1 = n1;
        }
#pragma unroll
        for (int mf = 0; mf < 2; ++mf)
#pragma unroll
            for (int nf = 0; nf < NF; ++nf) {
                int col = colbase + nf * 16 + l15;
#pragma unroll
                for (int r = 0; r < 4; ++r) {
                    int row = row0 + mf * 16 + lhi * 4 + r;
                    if (row < M) Cb[(size_t)row * NCOL + col] = (bf16_t)acc[mf][nf][r];
                }
            }
    }
}

// ---------- fused interaction block: x = x + agg@Wout; x = x + gelu(gelu(x@W1+b1)@W2+b2) ----------
// 512 threads = 8 waves; wave owns 32 output cols; 32-row tiles; B in VGPRs; LDS for intermediates.
__global__ __launch_bounds__(512, 2) void block_fused(
    const bf16_t* __restrict__ aggb, float* __restrict__ x, bf16_t* __restrict__ xb,
    const bf16_t* __restrict__ woutt, const bf16_t* __restrict__ fc1t,
    const bf16_t* __restrict__ fc2t, const float* __restrict__ b1, const float* __restrict__ b2,
    int M) {
    __shared__ bf16_t lds1[32][264];
    __shared__ bf16_t lds2[32][264];
    const int t = threadIdx.x, wave = t >> 6, lane = t & 63;
    const int l15 = lane & 15, lhi = lane >> 4;
    const int cb = wave * 32;

    bf16x8 bw[2][2], br1[8][2], br2[8][2];
#pragma unroll
    for (int ks = 0; ks < 2; ++ks)
#pragma unroll
        for (int nf = 0; nf < 2; ++nf)
            bw[ks][nf] = *(const bf16x8*)(woutt + (size_t)(cb + nf * 16 + l15) * 64 + ks * 32 + lhi * 8);
#pragma unroll
    for (int ks = 0; ks < 8; ++ks)
#pragma unroll
        for (int nf = 0; nf < 2; ++nf) {
            br1[ks][nf] = *(const bf16x8*)(fc1t + (size_t)(cb + nf * 16 + l15) * 256 + ks * 32 + lhi * 8);
            br2[ks][nf] = *(const bf16x8*)(fc2t + (size_t)(cb + nf * 16 + l15) * 256 + ks * 32 + lhi * 8);
        }
    float bias1[2], bias2[2];
#pragma unroll
    for (int nf = 0; nf < 2; ++nf) {
        bias1[nf] = b1[cb + nf * 16 + l15];
        bias2[nf] = b2[cb + nf * 16 + l15];
    }

    const bf16x8 z8 = zero8();
    for (int row0 = blockIdx.x * 32; row0 < M; row0 += gridDim.x * 32) {
        const int r0 = row0 + l15, r1 = row0 + 16 + l15;
        const bool g0 = r0 < M, g1 = r1 < M;

        // ---- Wout projection (K=64) ----
        f32x4 h[2][2];
#pragma unroll
        for (int mf = 0; mf < 2; ++mf)
#pragma unroll
            for (int nf = 0; nf < 2; ++nf) h[mf][nf] = (f32x4){0.f, 0.f, 0.f, 0.f};
#pragma unroll
        for (int ks = 0; ks < 2; ++ks) {
            bf16x8 a0 = g0 ? *(const bf16x8*)(aggb + (size_t)r0 * 64 + ks * 32 + lhi * 8) : z8;
            bf16x8 a1 = g1 ? *(const bf16x8*)(aggb + (size_t)r1 * 64 + ks * 32 + lhi * 8) : z8;
#pragma unroll
            for (int nf = 0; nf < 2; ++nf) {
                h[0][nf] = __builtin_amdgcn_mfma_f32_16x16x32_bf16(a0, bw[ks][nf], h[0][nf], 0, 0, 0);
                h[1][nf] = __builtin_amdgcn_mfma_f32_16x16x32_bf16(a1, bw[ks][nf], h[1][nf], 0, 0, 0);
            }
        }
        // ---- + residual x, stage fc1 input ----
#pragma unroll
        for (int mf = 0; mf < 2; ++mf)
#pragma unroll
            for (int nf = 0; nf < 2; ++nf) {
                int col = cb + nf * 16 + l15;
#pragma unroll
                for (int r = 0; r < 4; ++r) {
                    int lrow = mf * 16 + lhi * 4 + r;
                    int row = row0 + lrow;
                    float hv = h[mf][nf][r];
                    if (row < M) hv += x[(size_t)row * 256 + col];
                    h[mf][nf][r] = hv;
                    lds1[lrow][col] = (bf16_t)hv;
                }
            }
        __syncthreads();  // B1
        // ---- fc1 ----
        f32x4 acc[2][2];
#pragma unroll
        for (int mf = 0; mf < 2; ++mf)
#pragma unroll
            for (int nf = 0; nf < 2; ++nf) acc[mf][nf] = (f32x4){0.f, 0.f, 0.f, 0.f};
#pragma unroll
        for (int ks = 0; ks < 8; ++ks) {
            bf16x8 a0 = *(const bf16x8*)&lds1[l15][ks * 32 + lhi * 8];
            bf16x8 a1 = *(const bf16x8*)&lds1[16 + l15][ks * 32 + lhi * 8];
#pragma unroll
            for (int nf = 0; nf < 2; ++nf) {
                acc[0][nf] = __builtin_amdgcn_mfma_f32_16x16x32_bf16(a0, br1[ks][nf], acc[0][nf], 0, 0, 0);
                acc[1][nf] = __builtin_amdgcn_mfma_f32_16x16x32_bf16(a1, br1[ks][nf], acc[1][nf], 0, 0, 0);
            }
        }
#pragma unroll
        for (int mf = 0; mf < 2; ++mf)
#pragma unroll
            for (int nf = 0; nf < 2; ++nf) {
                int col = cb + nf * 16 + l15;
#pragma unroll
                for (int r = 0; r < 4; ++r)
                    lds2[mf * 16 + lhi * 4 + r][col] = (bf16_t)gelu_fast(acc[mf][nf][r] + bias1[nf]);
            }
        __syncthreads();  // B2
        // ---- fc2 + residual epilogue ----
#pragma unroll
        for (int mf = 0; mf < 2; ++mf)
#pragma unroll
            for (int nf = 0; nf < 2; ++nf) acc[mf][nf] = (f32x4){0.f, 0.f, 0.f, 0.f};
#pragma unroll
        for (int ks = 0; ks < 8; ++ks) {
            bf16x8 a0 = *(const bf16x8*)&lds2[l15][ks * 32 + lhi * 8];
            bf16x8 a1 = *(const bf16x8*)&lds2[16 + l15][ks * 32 + lhi * 8];
#pragma unroll
            for (int nf = 0; nf < 2; ++nf) {
                acc[0][nf] = __builtin_amdgcn_mfma_f32_16x16x32_bf16(a0, br2[ks][nf], acc[0][nf], 0, 0, 0);
                acc[1][nf] = __builtin_amdgcn_mfma_f32_16x16x32_bf16(a1, br2[ks][nf], acc[1][nf], 0, 0, 0);
            }
        }
#pragma unroll
        for (int mf = 0; mf < 2; ++mf)
#pragma unroll
            for (int nf = 0; nf < 2; ++nf) {
                int col = cb + nf * 16 + l15;
#pragma unroll
                for (int r = 0; r < 4; ++r) {
                    int row = row0 + mf * 16 + lhi * 4 + r;
                    if (row < M) {
                        float o = h[mf][nf][r] + gelu_fast(acc[mf][nf][r] + bias2[nf]);
                        x[(size_t)row * 256 + col] = o;
                        xb[(size_t)row * 256 + col] = (bf16_t)o;
                    }
                }
            }
        __syncthreads();  // protect lds1/lds2 for next tile
    }
}

// ---------- fused init: embed -> fc0.1 -> fc0.2 (no residual) ----------
__global__ __launch_bounds__(512, 2) void fc0_fused(
    const int* __restrict__ z, const float* __restrict__ table, const float* __restrict__ embW,
    const float* __restrict__ embb, const bf16_t* __restrict__ fc1t,
    const bf16_t* __restrict__ fc2t, const float* __restrict__ b1, const float* __restrict__ b2,
    float* __restrict__ x, bf16_t* __restrict__ xb, int M) {
    __shared__ bf16_t lds1[32][264];
    __shared__ bf16_t lds2[32][264];
    const int t = threadIdx.x, wave = t >> 6, lane = t & 63;
    const int l15 = lane & 15, lhi = lane >> 4;
    const int cb = wave * 32;
    const int erow = t >> 4, ecol0 = (t & 15) * 16;

    bf16x8 br1[8][2], br2[8][2];
#pragma unroll
    for (int ks = 0; ks < 8; ++ks)
#pragma unroll
        for (int nf = 0; nf < 2; ++nf) {
            br1[ks][nf] = *(const bf16x8*)(fc1t + (size_t)(cb + nf * 16 + l15) * 256 + ks * 32 + lhi * 8);
            br2[ks][nf] = *(const bf16x8*)(fc2t + (size_t)(cb + nf * 16 + l15) * 256 + ks * 32 + lhi * 8);
        }
    float bias1[2], bias2[2];
#pragma unroll
    for (int nf = 0; nf < 2; ++nf) {
        bias1[nf] = b1[cb + nf * 16 + l15];
        bias2[nf] = b2[cb + nf * 16 + l15];
    }

    for (int row0 = blockIdx.x * 32; row0 < M; row0 += gridDim.x * 32) {
        // ---- embed into lds1 ----
        int grow = row0 + erow;
        if (grow < M) {
            int zi = z[grow];
            float tr[5];
#pragma unroll
            for (int hh = 0; hh < 5; ++hh) tr[hh] = table[zi * 5 + hh];
#pragma unroll
            for (int c = 0; c < 16; ++c) {
                int col = ecol0 + c;
                float a = embb[col];
#pragma unroll
                for (int hh = 0; hh < 5; ++hh) a += tr[hh] * embW[hh * 256 + col];
                lds1[erow][col] = (bf16_t)a;
            }
        } else {
#pragma unroll
            for (int c = 0; c < 16; ++c) lds1[erow][ecol0 + c] = (bf16_t)0.f;
        }
        __syncthreads();
        // ---- fc0.1 ----
        f32x4 acc[2][2];
#pragma unroll
        for (int mf = 0; mf < 2; ++mf)
#pragma unroll
            for (int nf = 0; nf < 2; ++nf) acc[mf][nf] = (f32x4){0.f, 0.f, 0.f, 0.f};
#pragma unroll
        for (int ks = 0; ks < 8; ++ks) {
            bf16x8 a0 = *(const bf16x8*)&lds1[l15][ks * 32 + lhi * 8];
            bf16x8 a1 = *(const bf16x8*)&lds1[16 + l15][ks * 32 + lhi * 8];
#pragma unroll
            for (int nf = 0; nf < 2; ++nf) {
                acc[0][nf] = __builtin_amdgcn_mfma_f32_16x16x32_bf16(a0, br1[ks][nf], acc[0][nf], 0, 0, 0);
                acc[1][nf] = __builtin_amdgcn_mfma_f32_16x16x32_bf16(a1, br1[ks][nf], acc[1][nf], 0, 0, 0);
            }
        }
#pragma unroll
        for (int mf = 0; mf < 2; ++mf)
#pragma unroll
            for (int nf = 0; nf < 2; ++nf) {
                int col = cb + nf * 16 + l15;
#pragma unroll
                for (int r = 0; r < 4; ++r)
                    lds2[mf * 16 + lhi * 4 + r][col] = (bf16_t)gelu_fast(acc[mf][nf][r] + bias1[nf]);
            }
        __syncthreads();
        // ---- fc0.2 ----
#pragma unroll
        for (int mf = 0; mf < 2; ++mf)
#pragma unroll
            for (int nf = 0; nf < 2; ++nf) acc[mf][nf] = (f32x4){0.f, 0.f, 0.f, 0.f};
#pragma unroll
        for (int ks = 0; ks < 8; ++ks) {
            bf16x8 a0 = *(const bf16x8*)&lds2[l15][ks * 32 + lhi * 8];
            bf16x8 a1 = *(const bf16x8*)&lds2[16 + l15][ks * 32 + lhi * 8];
#pragma unroll
            for (int nf = 0; nf < 2; ++nf) {
                acc[0][nf] = __builtin_amdgcn_mfma_f32_16x16x32_bf16(a0, br2[ks][nf], acc[0][nf], 0, 0, 0);
                acc[1][nf] = __builtin_amdgcn_mfma_f32_16x16x32_bf16(a1, br2[ks][nf], acc[1][nf], 0, 0, 0);
            }
        }
#pragma unroll
        for (int mf = 0; mf < 2; ++mf)
#pragma unroll
            for (int nf = 0; nf < 2; ++nf) {
                int col = cb + nf * 16 + l15;
#pragma unroll
                for (int r = 0; r < 4; ++r) {
                    int row = row0 + mf * 16 + lhi * 4 + r;
                    if (row < M) {
                        float o = gelu_fast(acc[mf][nf][r] + bias2[nf]);
                        x[(size_t)row * 256 + col] = o;
                        xb[(size_t)row * 256 + col] = (bf16_t)o;
                    }
                }
            }
        __syncthreads();
    }
}

// ---------- CSR build ----------
__global__ void count_kernel(const int* __restrict__ ei, int* __restrict__ deg, int E) {
    int e = blockIdx.x * 256 + threadIdx.x;
    if (e < E) atomicAdd(&deg[ei[e]], 1);
}

__global__ void scan_local(const int* __restrict__ deg, int* __restrict__ rs,
                           int* __restrict__ bsum, int N) {
    __shared__ int sd[1024];
    int t = threadIdx.x, i = blockIdx.x * 1024 + t;
    int val = (i < N) ? deg[i] : 0;
    sd[t] = val;
    __syncthreads();
    for (int off = 1; off < 1024; off <<= 1) {
        int tv = (t >= off) ? sd[t - off] : 0;
        __syncthreads();
        sd[t] += tv;
        __syncthreads();
    }
    if (i < N) rs[i] = sd[t] - val;
    if (t == 1023) bsum[blockIdx.x] = sd[1023];
}

__global__ void scan_bsums(int* __restrict__ bsum, int nb) {
    if (threadIdx.x == 0) {
        int run = 0;
        for (int b = 0; b < nb; ++b) {
            int v = bsum[b];
            bsum[b] = run;
            run += v;
        }
        bsum[nb] = run;
    }
}

__global__ void scan_add(int* __restrict__ rs, const int* __restrict__ bsum, int N) {
    int i = blockIdx.x * 1024 + threadIdx.x;
    if (i < N) rs[i] += bsum[blockIdx.x];
    if (i == 0) rs[N] = bsum[gridDim.x];
}

__global__ void fill_kernel(const int* __restrict__ ei, const int* __restrict__ row_start,
                            int* __restrict__ cursor, int* __restrict__ csr_eid,
                            int* __restrict__ csr_j, int E) {
    int e = blockIdx.x * 256 + threadIdx.x;
    if (e < E) {
        int i = ei[e];
        int p = atomicAdd(&cursor[i], 1);
        int o = row_start[i] + p;
        csr_eid[o] = e;
        csr_j[o] = ei[E + e];
    }
}

// ---------- rbf in CSR order (bf16, rows padded to 16 elems / 32B, pad zeroed) ----------
__global__ void rbf_csr_kernel(const int* __restrict__ csr_eid, const int* __restrict__ ei,
                               const float* __restrict__ pos, const float* __restrict__ freqs,
                               bf16_t* __restrict__ rbf_csr, int E) {
    int idx = blockIdx.x * 256 + threadIdx.x;
    if (idx >= E) return;
    int e = csr_eid[idx];
    int i = ei[e], j = ei[E + e];
    float dx = pos[i * 3 + 0] - pos[j * 3 + 0];
    float dy = pos[i * 3 + 1] - pos[j * 3 + 1];
    float dz = pos[i * 3 + 2] - pos[j * 3 + 2];
    float dist = sqrtf(dx * dx + dy * dy + dz * dz + 1e-12f);
    float x = dist * 0.2f;
    float x4 = (x * x) * (x * x);
    float env = 1.0f / x + x4 * (-21.0f + x * (35.0f - 15.0f * x));
    bf16x8 lo, hi;
#pragma unroll
    for (int r = 0; r < 8; ++r) lo[r] = (bf16_t)(env * sinf(freqs[r] * x));
#pragma unroll
    for (int r = 0; r < 4; ++r) hi[r] = (bf16_t)(env * sinf(freqs[8 + r] * x));
#pragma unroll
    for (int r = 4; r < 8; ++r) hi[r] = (bf16_t)0.f;
    bf16_t* dst = rbf_csr + (size_t)idx * 16;
    *(bf16x8*)dst = lo;
    *(bf16x8*)(dst + 8) = hi;
}

// ---------- message gather: MFMA-based gate (rbf@Wrbf) + coalesced v gather ----------
__global__ __launch_bounds__(256) void msg_kernel(const int* __restrict__ row_start,
                                                  const int* __restrict__ csr_j,
                                                  const bf16_t* __restrict__ rbf_csr,
                                                  const bf16_t* __restrict__ v,
                                                  const float* __restrict__ Wrbf,
                                                  bf16_t* __restrict__ agg, int N, int E) {
    const int wave = threadIdx.x >> 6, lane = threadIdx.x & 63;
    const int l15 = lane & 15, lhi = lane >> 4;
    const int nd = blockIdx.x * 4 + wave;
    if (nd >= N) return;
    bf16x8 wrb[4];
#pragma unroll
    for (int nf = 0; nf < 4; ++nf) {
#pragma unroll
        for (int j = 0; j < 8; ++j) {
            int k = lhi * 8 + j;
            wrb[nf][j] = (k < 12) ? (bf16_t)Wrbf[k * 64 + l15 * 4 + nf] : (bf16_t)0.f;
        }
    }
    const int s = row_start[nd], e = row_start[nd + 1];
    float acc[4] = {0.f, 0.f, 0.f, 0.f};
    const bf16x8 z8 = zero8();
    for (int g0 = s; g0 < e; g0 += 16) {
        int ea = g0 + l15;
        bf16x8 af = (lhi < 2 && ea < e) ? *(const bf16x8*)(rbf_csr + (size_t)ea * 16 + lhi * 8) : z8;
        f32x4 gacc[4];
#pragma unroll
        for (int nf = 0; nf < 4; ++nf)
            gacc[nf] = __builtin_amdgcn_mfma_f32_16x16x32_bf16(af, wrb[nf],
                                                               (f32x4){0.f, 0.f, 0.f, 0.f}, 0, 0, 0);
#pragma unroll
        for (int r = 0; r < 4; ++r) {
            int er = g0 + lhi * 4 + r;
            int jj = csr_j[er < E ? er : E - 1];
            bf16x4 vj = *(const bf16x4*)(v + (size_t)jj * 64 + l15 * 4);
#pragma unroll
            for (int nf = 0; nf < 4; ++nf) acc[nf] += gacc[nf][r] * (float)vj[nf];
        }
    }
#pragma unroll
    for (int nf = 0; nf < 4; ++nf) {
        acc[nf] += __shfl_xor(acc[nf], 16, 64);
        acc[nf] += __shfl_xor(acc[nf], 32, 64);
    }
    if (lhi == 0) {
        bf16x4 o;
#pragma unroll
        for (int nf = 0; nf < 4; ++nf) o[nf] = (bf16_t)acc[nf];
        *(bf16x4*)(agg + (size_t)nd * 64 + l15 * 4) = o;
    }
}

extern "C" void kernel_launch(void* const* d_in, const int* in_sizes, int n_in, void* d_out,
                              int out_size, void* d_ws, size_t ws_size, hipStream_t stream) {
    const int* z = (const int*)d_in[0];
    const float* pos = (const float*)d_in[1];
    const int* ei = (const int*)d_in[4];
    const float* emb_table = (const float*)d_in[5];
    const float* emb_W = (const float*)d_in[6];
    const float* emb_b = (const float*)d_in[7];
    const float* freqs = (const float*)d_in[8];
    const float* fc0_W = (const float*)d_in[9];
    const float* fc0_b = (const float*)d_in[10];
    const float* conv_Wv = (const float*)d_in[11];
    const float* conv_Wrbf = (const float*)d_in[12];
    const float* conv_Wout = (const float*)d_in[13];
    const float* fc_W = (const float*)d_in[14];
    const float* fc_b = (const float*)d_in[15];
    float* x = (float*)d_out;

    const int N = in_sizes[0];
    const int E = in_sizes[4] / 2;

    // ---- workspace carve ----
    char* wsp = (char*)d_ws;
    auto alloc = [&](size_t bytes) {
        void* p = (void*)wsp;
        wsp += (bytes + 255) & ~(size_t)255;
        return p;
    };
    bf16_t* xb = (bf16_t*)alloc((size_t)N * DD * 2);
    bf16_t* vb = (bf16_t*)alloc((size_t)N * MM * 2);
    bf16_t* aggb = (bf16_t*)alloc((size_t)N * MM * 2);
    bf16_t* rbf_csr = (bf16_t*)alloc((size_t)E * 16 * 2);
    int* deg = (int*)alloc((size_t)N * 4);
    int* cursor = (int*)alloc((size_t)N * 4);
    int* row_start = (int*)alloc((size_t)(N + 1) * 4);
    int* bsum = (int*)alloc((size_t)256 * 4);
    int* csr_eid = (int*)alloc((size_t)E * 4);
    int* csr_j = (int*)alloc((size_t)E * 4);
    bf16_t* wbf = (bf16_t*)alloc((size_t)786432 * 2);
    bf16_t* fc0t = wbf;              // 2 x [256][256]
    bf16_t* fct = wbf + 2 * 65536;   // 8 x [256][256]
    bf16_t* wvt = wbf + 10 * 65536;  // 4 x [64 cols][256 k]
    bf16_t* wott = wvt + 4 * 16384;  // 4 x [256 cols][64 k]

    // ---- weight prep ----
    cvt_transpose_kernel<<<dim3(256, 2), 256, 0, stream>>>(fc0_W, fc0t, 256, 256);
    cvt_transpose_kernel<<<dim3(256, 8), 256, 0, stream>>>(fc_W, fct, 256, 256);
    cvt_transpose_kernel<<<dim3(64, 4), 256, 0, stream>>>(conv_Wv, wvt, 256, 64);
    cvt_transpose_kernel<<<dim3(64, 4), 256, 0, stream>>>(conv_Wout, wott, 64, 256);

    // ---- CSR by destination, rbf in CSR order ----
    hipMemsetAsync(deg, 0, (size_t)N * 4, stream);
    hipMemsetAsync(cursor, 0, (size_t)N * 4, stream);
    count_kernel<<<(E + 255) / 256, 256, 0, stream>>>(ei, deg, E);
    const int nb = (N + 1023) / 1024;
    scan_local<<<nb, 1024, 0, stream>>>(deg, row_start, bsum, N);
    scan_bsums<<<1, 64, 0, stream>>>(bsum, nb);
    scan_add<<<nb, 1024, 0, stream>>>(row_start, bsum, N);
    fill_kernel<<<(E + 255) / 256, 256, 0, stream>>>(ei, row_start, cursor, csr_eid, csr_j, E);
    rbf_csr_kernel<<<(E + 255) / 256, 256, 0, stream>>>(csr_eid, ei, pos, freqs, rbf_csr, E);

    // ---- init: embed + fc0 (2 gelu layers) ----
    const int GF = 512;
    fc0_fused<<<GF, 512, 0, stream>>>(z, emb_table, emb_W, emb_b, fc0t, fc0t + 65536, fc0_b,
                                      fc0_b + 256, x, xb, N);

    // ---- interaction blocks ----
    for (int n = 0; n < 4; ++n) {
        gemm_rb<256, 64><<<512, 256, 0, stream>>>(xb, wvt + n * 16384, vb, N);
        msg_kernel<<<(N + 3) / 4, 256, 0, stream>>>(row_start, csr_j, rbf_csr, vb,
                                                    conv_Wrbf + n * RR * MM, aggb, N, E);
        block_fused<<<GF, 512, 0, stream>>>(aggb, x, xb, wott + n * 16384, fct + (n * 2) * 65536,
                                            fct + (n * 2 + 1) * 65536, fc_b + n * 2 * 256,
                                            fc_b + (n * 2 + 1) * 256, N);
    }
}

// Round 7
// 938.060 us; speedup vs baseline: 1.3404x; 1.1196x over previous
//
#include <hip/hip_runtime.h>
#include <hip/hip_bf16.h>

typedef __bf16 bf16_t;
typedef bf16_t bf16x8 __attribute__((ext_vector_type(8)));
typedef bf16_t bf16x4 __attribute__((ext_vector_type(4)));
typedef float f32x4 __attribute__((ext_vector_type(4)));

#define DD 256
#define MM 64
#define RR 12

__device__ __forceinline__ float gelu_fast(float x) {
    // tanh-approx gelu via exp identity: tanh(u) = sign(u)*(1-e^{-2|u|})/(1+e^{-2|u|})
    float u = x * (0.7978845608f + 0.0356774081f * x * x);
    float t = __expf(-2.f * fabsf(u));
    float th = (1.f - t) / (1.f + t);
    th = copysignf(th, u);
    return 0.5f * x * (1.f + th);
}

__device__ __forceinline__ bf16x8 zero8() {
    bf16x8 z;
#pragma unroll
    for (int i = 0; i < 8; ++i) z[i] = (bf16_t)0.f;
    return z;
}

// ---------- weight prep: fp32 [K][C] -> bf16 transposed [C][K], batched over blockIdx.y ----------
__global__ void cvt_transpose_kernel(const float* __restrict__ src, bf16_t* __restrict__ dst,
                                     int K, int C) {
    int m = blockIdx.y;
    const float* s = src + (size_t)m * K * C;
    bf16_t* d = dst + (size_t)m * K * C;
    int idx = blockIdx.x * 256 + threadIdx.x;
    if (idx < K * C) {
        int k = idx / C, c = idx - k * C;
        d[c * K + k] = (bf16_t)s[idx];
    }
}

// ---------- register-B MFMA GEMM (used for Wv only) ----------
template <int K, int NCOL>
__global__ __launch_bounds__(256, 4) void gemm_rb(const bf16_t* __restrict__ A,
                                                  const bf16_t* __restrict__ Wt,
                                                  bf16_t* __restrict__ Cb, int M) {
    constexpr int NSTEP = K / 32;
    constexpr int NF = NCOL / 64;
    const int t = threadIdx.x;
    const int wave = t >> 6, lane = t & 63;
    const int l15 = lane & 15, lhi = lane >> 4;
    const int colbase = wave * (NCOL / 4);

    bf16x8 bfr[NSTEP][NF];
#pragma unroll
    for (int ks = 0; ks < NSTEP; ++ks)
#pragma unroll
        for (int nf = 0; nf < NF; ++nf)
            bfr[ks][nf] =
                *(const bf16x8*)(Wt + (size_t)(colbase + nf * 16 + l15) * K + ks * 32 + lhi * 8);

    const bf16x8 z8 = zero8();
    for (int row0 = blockIdx.x * 32; row0 < M; row0 += gridDim.x * 32) {
        const int r0 = row0 + l15, r1 = row0 + 16 + l15;
        const bool g0 = r0 < M, g1 = r1 < M;
        const bf16_t* a0p = A + (size_t)r0 * K + lhi * 8;
        const bf16_t* a1p = A + (size_t)r1 * K + lhi * 8;

        f32x4 acc[2][NF];
#pragma unroll
        for (int mf = 0; mf < 2; ++mf)
#pragma unroll
            for (int nf = 0; nf < NF; ++nf) acc[mf][nf] = (f32x4){0.f, 0.f, 0.f, 0.f};

        bf16x8 a0 = g0 ? *(const bf16x8*)a0p : z8;
        bf16x8 a1 = g1 ? *(const bf16x8*)a1p : z8;
#pragma unroll
        for (int ks = 0; ks < NSTEP; ++ks) {
            bf16x8 n0 = z8, n1 = z8;
            if (ks + 1 < NSTEP) {
                n0 = g0 ? *(const bf16x8*)(a0p + (ks + 1) * 32) : z8;
                n1 = g1 ? *(const bf16x8*)(a1p + (ks + 1) * 32) : z8;
            }
#pragma unroll
            for (int nf = 0; nf < NF; ++nf)
                acc[0][nf] = __builtin_amdgcn_mfma_f32_16x16x32_bf16(a0, bfr[ks][nf], acc[0][nf], 0, 0, 0);
#pragma unroll
            for (int nf = 0; nf < NF; ++nf)
                acc[1][nf] = __builtin_amdgcn_mfma_f32_16x16x32_bf16(a1, bfr[ks][nf], acc[1][nf], 0, 0, 0);
            a0 = n0;
            a1 = n1;
        }
#pragma unroll
        for (int mf = 0; mf < 2; ++mf)
#pragma unroll
            for (int nf = 0; nf < NF; ++nf) {
                int col = colbase + nf * 16 + l15;
#pragma unroll
                for (int r = 0; r < 4; ++r) {
                    int row = row0 + mf * 16 + lhi * 4 + r;
                    if (row < M) Cb[(size_t)row * NCOL + col] = (bf16_t)acc[mf][nf][r];
                }
            }
    }
}

// ---------- fused interaction block: x = x + agg@Wout; x = x + gelu(gelu(x@W1+b1)@W2+b2) ----------
// 512 threads = 8 waves; wave owns 32 output cols; 32-row tiles; B in VGPRs; LDS for intermediates.
// Cross-tile register prefetch of aggb/x hides global latency under fc1+fc2 MFMA.
__global__ __launch_bounds__(512, 2) void block_fused(
    const bf16_t* __restrict__ aggb, float* __restrict__ x, bf16_t* __restrict__ xb,
    const bf16_t* __restrict__ woutt, const bf16_t* __restrict__ fc1t,
    const bf16_t* __restrict__ fc2t, const float* __restrict__ b1, const float* __restrict__ b2,
    int M) {
    __shared__ bf16_t lds1[32][264];
    __shared__ bf16_t lds2[32][264];
    const int t = threadIdx.x, wave = t >> 6, lane = t & 63;
    const int l15 = lane & 15, lhi = lane >> 4;
    const int cb = wave * 32;
    const int STRIDE = gridDim.x * 32;

    bf16x8 bw[2][2], br1[8][2], br2[8][2];
#pragma unroll
    for (int ks = 0; ks < 2; ++ks)
#pragma unroll
        for (int nf = 0; nf < 2; ++nf)
            bw[ks][nf] = *(const bf16x8*)(woutt + (size_t)(cb + nf * 16 + l15) * 64 + ks * 32 + lhi * 8);
#pragma unroll
    for (int ks = 0; ks < 8; ++ks)
#pragma unroll
        for (int nf = 0; nf < 2; ++nf) {
            br1[ks][nf] = *(const bf16x8*)(fc1t + (size_t)(cb + nf * 16 + l15) * 256 + ks * 32 + lhi * 8);
            br2[ks][nf] = *(const bf16x8*)(fc2t + (size_t)(cb + nf * 16 + l15) * 256 + ks * 32 + lhi * 8);
        }
    float bias1[2], bias2[2];
#pragma unroll
    for (int nf = 0; nf < 2; ++nf) {
        bias1[nf] = b1[cb + nf * 16 + l15];
        bias2[nf] = b2[cb + nf * 16 + l15];
    }

    const bf16x8 z8 = zero8();
    bf16x8 pfa[2][2];
    float pfx[2][2][4];
    auto PREFETCH = [&](int r0) {
        const int rr0 = r0 + l15, rr1 = r0 + 16 + l15;
#pragma unroll
        for (int ks = 0; ks < 2; ++ks) {
            pfa[0][ks] = (rr0 < M) ? *(const bf16x8*)(aggb + (size_t)rr0 * 64 + ks * 32 + lhi * 8) : z8;
            pfa[1][ks] = (rr1 < M) ? *(const bf16x8*)(aggb + (size_t)rr1 * 64 + ks * 32 + lhi * 8) : z8;
        }
#pragma unroll
        for (int mf = 0; mf < 2; ++mf)
#pragma unroll
            for (int nf = 0; nf < 2; ++nf)
#pragma unroll
                for (int r = 0; r < 4; ++r) {
                    int row = r0 + mf * 16 + lhi * 4 + r;
                    pfx[mf][nf][r] = (row < M) ? x[(size_t)row * 256 + cb + nf * 16 + l15] : 0.f;
                }
    };

    PREFETCH(blockIdx.x * 32);
    for (int row0 = blockIdx.x * 32; row0 < M; row0 += STRIDE) {
        // ---- phase A: h = agg@Wout + x (all operands already in registers) ----
        f32x4 h[2][2];
#pragma unroll
        for (int mf = 0; mf < 2; ++mf)
#pragma unroll
            for (int nf = 0; nf < 2; ++nf) h[mf][nf] = (f32x4){0.f, 0.f, 0.f, 0.f};
#pragma unroll
        for (int ks = 0; ks < 2; ++ks)
#pragma unroll
            for (int nf = 0; nf < 2; ++nf) {
                h[0][nf] = __builtin_amdgcn_mfma_f32_16x16x32_bf16(pfa[0][ks], bw[ks][nf], h[0][nf], 0, 0, 0);
                h[1][nf] = __builtin_amdgcn_mfma_f32_16x16x32_bf16(pfa[1][ks], bw[ks][nf], h[1][nf], 0, 0, 0);
            }
#pragma unroll
        for (int mf = 0; mf < 2; ++mf)
#pragma unroll
            for (int nf = 0; nf < 2; ++nf) {
                int col = cb + nf * 16 + l15;
#pragma unroll
                for (int r = 0; r < 4; ++r) {
                    int lrow = mf * 16 + lhi * 4 + r;
                    float hv = h[mf][nf][r] + pfx[mf][nf][r];
                    h[mf][nf][r] = hv;
                    lds1[lrow][col] = (bf16_t)hv;
                }
            }
        __syncthreads();  // B1
        if (row0 + STRIDE < M) PREFETCH(row0 + STRIDE);  // lands under fc1+fc2 MFMA
        // ---- fc1 ----
        f32x4 acc[2][2];
#pragma unroll
        for (int mf = 0; mf < 2; ++mf)
#pragma unroll
            for (int nf = 0; nf < 2; ++nf) acc[mf][nf] = (f32x4){0.f, 0.f, 0.f, 0.f};
#pragma unroll
        for (int ks = 0; ks < 8; ++ks) {
            bf16x8 a0 = *(const bf16x8*)&lds1[l15][ks * 32 + lhi * 8];
            bf16x8 a1 = *(const bf16x8*)&lds1[16 + l15][ks * 32 + lhi * 8];
#pragma unroll
            for (int nf = 0; nf < 2; ++nf) {
                acc[0][nf] = __builtin_amdgcn_mfma_f32_16x16x32_bf16(a0, br1[ks][nf], acc[0][nf], 0, 0, 0);
                acc[1][nf] = __builtin_amdgcn_mfma_f32_16x16x32_bf16(a1, br1[ks][nf], acc[1][nf], 0, 0, 0);
            }
        }
#pragma unroll
        for (int mf = 0; mf < 2; ++mf)
#pragma unroll
            for (int nf = 0; nf < 2; ++nf) {
                int col = cb + nf * 16 + l15;
#pragma unroll
                for (int r = 0; r < 4; ++r)
                    lds2[mf * 16 + lhi * 4 + r][col] = (bf16_t)gelu_fast(acc[mf][nf][r] + bias1[nf]);
            }
        __syncthreads();  // B2
        // ---- fc2 + residual epilogue ----
#pragma unroll
        for (int mf = 0; mf < 2; ++mf)
#pragma unroll
            for (int nf = 0; nf < 2; ++nf) acc[mf][nf] = (f32x4){0.f, 0.f, 0.f, 0.f};
#pragma unroll
        for (int ks = 0; ks < 8; ++ks) {
            bf16x8 a0 = *(const bf16x8*)&lds2[l15][ks * 32 + lhi * 8];
            bf16x8 a1 = *(const bf16x8*)&lds2[16 + l15][ks * 32 + lhi * 8];
#pragma unroll
            for (int nf = 0; nf < 2; ++nf) {
                acc[0][nf] = __builtin_amdgcn_mfma_f32_16x16x32_bf16(a0, br2[ks][nf], acc[0][nf], 0, 0, 0);
                acc[1][nf] = __builtin_amdgcn_mfma_f32_16x16x32_bf16(a1, br2[ks][nf], acc[1][nf], 0, 0, 0);
            }
        }
#pragma unroll
        for (int mf = 0; mf < 2; ++mf)
#pragma unroll
            for (int nf = 0; nf < 2; ++nf) {
                int col = cb + nf * 16 + l15;
#pragma unroll
                for (int r = 0; r < 4; ++r) {
                    int row = row0 + mf * 16 + lhi * 4 + r;
                    if (row < M) {
                        float o = h[mf][nf][r] + gelu_fast(acc[mf][nf][r] + bias2[nf]);
                        x[(size_t)row * 256 + col] = o;
                        xb[(size_t)row * 256 + col] = (bf16_t)o;
                    }
                }
            }
        // no trailing barrier: next-tile lds1 writes are ordered by next B1/B2 (round-4 proof)
    }
}

// ---------- fused init: embed -> fc0.1 -> fc0.2 (no residual) ----------
__global__ __launch_bounds__(512, 2) void fc0_fused(
    const int* __restrict__ z, const float* __restrict__ table, const float* __restrict__ embW,
    const float* __restrict__ embb, const bf16_t* __restrict__ fc1t,
    const bf16_t* __restrict__ fc2t, const float* __restrict__ b1, const float* __restrict__ b2,
    float* __restrict__ x, bf16_t* __restrict__ xb, int M) {
    __shared__ bf16_t lds1[32][264];
    __shared__ bf16_t lds2[32][264];
    const int t = threadIdx.x, wave = t >> 6, lane = t & 63;
    const int l15 = lane & 15, lhi = lane >> 4;
    const int cb = wave * 32;
    const int erow = t >> 4, ecol0 = (t & 15) * 16;

    bf16x8 br1[8][2], br2[8][2];
#pragma unroll
    for (int ks = 0; ks < 8; ++ks)
#pragma unroll
        for (int nf = 0; nf < 2; ++nf) {
            br1[ks][nf] = *(const bf16x8*)(fc1t + (size_t)(cb + nf * 16 + l15) * 256 + ks * 32 + lhi * 8);
            br2[ks][nf] = *(const bf16x8*)(fc2t + (size_t)(cb + nf * 16 + l15) * 256 + ks * 32 + lhi * 8);
        }
    float bias1[2], bias2[2];
#pragma unroll
    for (int nf = 0; nf < 2; ++nf) {
        bias1[nf] = b1[cb + nf * 16 + l15];
        bias2[nf] = b2[cb + nf * 16 + l15];
    }

    for (int row0 = blockIdx.x * 32; row0 < M; row0 += gridDim.x * 32) {
        // ---- embed into lds1 ----
        int grow = row0 + erow;
        if (grow < M) {
            int zi = z[grow];
            float tr[5];
#pragma unroll
            for (int hh = 0; hh < 5; ++hh) tr[hh] = table[zi * 5 + hh];
#pragma unroll
            for (int c = 0; c < 16; ++c) {
                int col = ecol0 + c;
                float a = embb[col];
#pragma unroll
                for (int hh = 0; hh < 5; ++hh) a += tr[hh] * embW[hh * 256 + col];
                lds1[erow][col] = (bf16_t)a;
            }
        } else {
#pragma unroll
            for (int c = 0; c < 16; ++c) lds1[erow][ecol0 + c] = (bf16_t)0.f;
        }
        __syncthreads();
        // ---- fc0.1 ----
        f32x4 acc[2][2];
#pragma unroll
        for (int mf = 0; mf < 2; ++mf)
#pragma unroll
            for (int nf = 0; nf < 2; ++nf) acc[mf][nf] = (f32x4){0.f, 0.f, 0.f, 0.f};
#pragma unroll
        for (int ks = 0; ks < 8; ++ks) {
            bf16x8 a0 = *(const bf16x8*)&lds1[l15][ks * 32 + lhi * 8];
            bf16x8 a1 = *(const bf16x8*)&lds1[16 + l15][ks * 32 + lhi * 8];
#pragma unroll
            for (int nf = 0; nf < 2; ++nf) {
                acc[0][nf] = __builtin_amdgcn_mfma_f32_16x16x32_bf16(a0, br1[ks][nf], acc[0][nf], 0, 0, 0);
                acc[1][nf] = __builtin_amdgcn_mfma_f32_16x16x32_bf16(a1, br1[ks][nf], acc[1][nf], 0, 0, 0);
            }
        }
#pragma unroll
        for (int mf = 0; mf < 2; ++mf)
#pragma unroll
            for (int nf = 0; nf < 2; ++nf) {
                int col = cb + nf * 16 + l15;
#pragma unroll
                for (int r = 0; r < 4; ++r)
                    lds2[mf * 16 + lhi * 4 + r][col] = (bf16_t)gelu_fast(acc[mf][nf][r] + bias1[nf]);
            }
        __syncthreads();
        // ---- fc0.2 ----
#pragma unroll
        for (int mf = 0; mf < 2; ++mf)
#pragma unroll
            for (int nf = 0; nf < 2; ++nf) acc[mf][nf] = (f32x4){0.f, 0.f, 0.f, 0.f};
#pragma unroll
        for (int ks = 0; ks < 8; ++ks) {
            bf16x8 a0 = *(const bf16x8*)&lds2[l15][ks * 32 + lhi * 8];
            bf16x8 a1 = *(const bf16x8*)&lds2[16 + l15][ks * 32 + lhi * 8];
#pragma unroll
            for (int nf = 0; nf < 2; ++nf) {
                acc[0][nf] = __builtin_amdgcn_mfma_f32_16x16x32_bf16(a0, br2[ks][nf], acc[0][nf], 0, 0, 0);
                acc[1][nf] = __builtin_amdgcn_mfma_f32_16x16x32_bf16(a1, br2[ks][nf], acc[1][nf], 0, 0, 0);
            }
        }
#pragma unroll
        for (int mf = 0; mf < 2; ++mf)
#pragma unroll
            for (int nf = 0; nf < 2; ++nf) {
                int col = cb + nf * 16 + l15;
#pragma unroll
                for (int r = 0; r < 4; ++r) {
                    int row = row0 + mf * 16 + lhi * 4 + r;
                    if (row < M) {
                        float o = gelu_fast(acc[mf][nf][r] + bias2[nf]);
                        x[(size_t)row * 256 + col] = o;
                        xb[(size_t)row * 256 + col] = (bf16_t)o;
                    }
                }
            }
    }
}

// ---------- CSR build ----------
__global__ void count_kernel(const int* __restrict__ ei, int* __restrict__ deg, int E) {
    int e = blockIdx.x * 256 + threadIdx.x;
    if (e < E) atomicAdd(&deg[ei[e]], 1);
}

__global__ void scan_local(const int* __restrict__ deg, int* __restrict__ rs,
                           int* __restrict__ bsum, int N) {
    __shared__ int sd[1024];
    int t = threadIdx.x, i = blockIdx.x * 1024 + t;
    int val = (i < N) ? deg[i] : 0;
    sd[t] = val;
    __syncthreads();
    for (int off = 1; off < 1024; off <<= 1) {
        int tv = (t >= off) ? sd[t - off] : 0;
        __syncthreads();
        sd[t] += tv;
        __syncthreads();
    }
    if (i < N) rs[i] = sd[t] - val;
    if (t == 1023) bsum[blockIdx.x] = sd[1023];
}

__global__ void scan_bsums(int* __restrict__ bsum, int nb) {
    if (threadIdx.x == 0) {
        int run = 0;
        for (int b = 0; b < nb; ++b) {
            int v = bsum[b];
            bsum[b] = run;
            run += v;
        }
        bsum[nb] = run;
    }
}

__global__ void scan_add(int* __restrict__ rs, const int* __restrict__ bsum, int N) {
    int i = blockIdx.x * 1024 + threadIdx.x;
    if (i < N) rs[i] += bsum[blockIdx.x];
    if (i == 0) rs[N] = bsum[gridDim.x];
}

__global__ void fill_kernel(const int* __restrict__ ei, const int* __restrict__ row_start,
                            int* __restrict__ cursor, int* __restrict__ csr_eid,
                            int* __restrict__ csr_j, int E) {
    int e = blockIdx.x * 256 + threadIdx.x;
    if (e < E) {
        int i = ei[e];
        int p = atomicAdd(&cursor[i], 1);
        int o = row_start[i] + p;
        csr_eid[o] = e;
        csr_j[o] = ei[E + e];
    }
}

// ---------- rbf in CSR order (bf16, rows padded to 16 elems / 32B, pad zeroed) ----------
__global__ void rbf_csr_kernel(const int* __restrict__ csr_eid, const int* __restrict__ ei,
                               const float* __restrict__ pos, const float* __restrict__ freqs,
                               bf16_t* __restrict__ rbf_csr, int E) {
    int idx = blockIdx.x * 256 + threadIdx.x;
    if (idx >= E) return;
    int e = csr_eid[idx];
    int i = ei[e], j = ei[E + e];
    float dx = pos[i * 3 + 0] - pos[j * 3 + 0];
    float dy = pos[i * 3 + 1] - pos[j * 3 + 1];
    float dz = pos[i * 3 + 2] - pos[j * 3 + 2];
    float dist = sqrtf(dx * dx + dy * dy + dz * dz + 1e-12f);
    float x = dist * 0.2f;
    float x4 = (x * x) * (x * x);
    float env = 1.0f / x + x4 * (-21.0f + x * (35.0f - 15.0f * x));
    bf16x8 lo, hi;
#pragma unroll
    for (int r = 0; r < 8; ++r) lo[r] = (bf16_t)(env * sinf(freqs[r] * x));
#pragma unroll
    for (int r = 0; r < 4; ++r) hi[r] = (bf16_t)(env * sinf(freqs[8 + r] * x));
#pragma unroll
    for (int r = 4; r < 8; ++r) hi[r] = (bf16_t)0.f;
    bf16_t* dst = rbf_csr + (size_t)idx * 16;
    *(bf16x8*)dst = lo;
    *(bf16x8*)(dst + 8) = hi;
}

// ---------- message gather: MFMA-based gate (rbf@Wrbf) + coalesced v gather ----------
__global__ __launch_bounds__(256) void msg_kernel(const int* __restrict__ row_start,
                                                  const int* __restrict__ csr_j,
                                                  const bf16_t* __restrict__ rbf_csr,
                                                  const bf16_t* __restrict__ v,
                                                  const float* __restrict__ Wrbf,
                                                  bf16_t* __restrict__ agg, int N, int E) {
    const int wave = threadIdx.x >> 6, lane = threadIdx.x & 63;
    const int l15 = lane & 15, lhi = lane >> 4;
    const int nd = blockIdx.x * 4 + wave;
    if (nd >= N) return;
    bf16x8 wrb[4];
#pragma unroll
    for (int nf = 0; nf < 4; ++nf) {
#pragma unroll
        for (int j = 0; j < 8; ++j) {
            int k = lhi * 8 + j;
            wrb[nf][j] = (k < 12) ? (bf16_t)Wrbf[k * 64 + l15 * 4 + nf] : (bf16_t)0.f;
        }
    }
    const int s = row_start[nd], e = row_start[nd + 1];
    float acc[4] = {0.f, 0.f, 0.f, 0.f};
    const bf16x8 z8 = zero8();
    for (int g0 = s; g0 < e; g0 += 16) {
        int ea = g0 + l15;
        bf16x8 af = (lhi < 2 && ea < e) ? *(const bf16x8*)(rbf_csr + (size_t)ea * 16 + lhi * 8) : z8;
        f32x4 gacc[4];
#pragma unroll
        for (int nf = 0; nf < 4; ++nf)
            gacc[nf] = __builtin_amdgcn_mfma_f32_16x16x32_bf16(af, wrb[nf],
                                                               (f32x4){0.f, 0.f, 0.f, 0.f}, 0, 0, 0);
#pragma unroll
        for (int r = 0; r < 4; ++r) {
            int er = g0 + lhi * 4 + r;
            int jj = csr_j[er < E ? er : E - 1];
            bf16x4 vj = *(const bf16x4*)(v + (size_t)jj * 64 + l15 * 4);
#pragma unroll
            for (int nf = 0; nf < 4; ++nf) acc[nf] += gacc[nf][r] * (float)vj[nf];
        }
    }
#pragma unroll
    for (int nf = 0; nf < 4; ++nf) {
        acc[nf] += __shfl_xor(acc[nf], 16, 64);
        acc[nf] += __shfl_xor(acc[nf], 32, 64);
    }
    if (lhi == 0) {
        bf16x4 o;
#pragma unroll
        for (int nf = 0; nf < 4; ++nf) o[nf] = (bf16_t)acc[nf];
        *(bf16x4*)(agg + (size_t)nd * 64 + l15 * 4) = o;
    }
}

extern "C" void kernel_launch(void* const* d_in, const int* in_sizes, int n_in, void* d_out,
                              int out_size, void* d_ws, size_t ws_size, hipStream_t stream) {
    const int* z = (const int*)d_in[0];
    const float* pos = (const float*)d_in[1];
    const int* ei = (const int*)d_in[4];
    const float* emb_table = (const float*)d_in[5];
    const float* emb_W = (const float*)d_in[6];
    const float* emb_b = (const float*)d_in[7];
    const float* freqs = (const float*)d_in[8];
    const float* fc0_W = (const float*)d_in[9];
    const float* fc0_b = (const float*)d_in[10];
    const float* conv_Wv = (const float*)d_in[11];
    const float* conv_Wrbf = (const float*)d_in[12];
    const float* conv_Wout = (const float*)d_in[13];
    const float* fc_W = (const float*)d_in[14];
    const float* fc_b = (const float*)d_in[15];
    float* x = (float*)d_out;

    const int N = in_sizes[0];
    const int E = in_sizes[4] / 2;

    // ---- workspace carve ----
    char* wsp = (char*)d_ws;
    auto alloc = [&](size_t bytes) {
        void* p = (void*)wsp;
        wsp += (bytes + 255) & ~(size_t)255;
        return p;
    };
    bf16_t* xb = (bf16_t*)alloc((size_t)N * DD * 2);
    bf16_t* vb = (bf16_t*)alloc((size_t)N * MM * 2);
    bf16_t* aggb = (bf16_t*)alloc((size_t)N * MM * 2);
    bf16_t* rbf_csr = (bf16_t*)alloc((size_t)E * 16 * 2);
    int* deg = (int*)alloc((size_t)N * 4);
    int* cursor = (int*)alloc((size_t)N * 4);
    int* row_start = (int*)alloc((size_t)(N + 1) * 4);
    int* bsum = (int*)alloc((size_t)256 * 4);
    int* csr_eid = (int*)alloc((size_t)E * 4);
    int* csr_j = (int*)alloc((size_t)E * 4);
    bf16_t* wbf = (bf16_t*)alloc((size_t)786432 * 2);
    bf16_t* fc0t = wbf;              // 2 x [256][256]
    bf16_t* fct = wbf + 2 * 65536;   // 8 x [256][256]
    bf16_t* wvt = wbf + 10 * 65536;  // 4 x [64 cols][256 k]
    bf16_t* wott = wvt + 4 * 16384;  // 4 x [256 cols][64 k]

    // ---- weight prep ----
    cvt_transpose_kernel<<<dim3(256, 2), 256, 0, stream>>>(fc0_W, fc0t, 256, 256);
    cvt_transpose_kernel<<<dim3(256, 8), 256, 0, stream>>>(fc_W, fct, 256, 256);
    cvt_transpose_kernel<<<dim3(64, 4), 256, 0, stream>>>(conv_Wv, wvt, 256, 64);
    cvt_transpose_kernel<<<dim3(64, 4), 256, 0, stream>>>(conv_Wout, wott, 64, 256);

    // ---- CSR by destination, rbf in CSR order ----
    hipMemsetAsync(deg, 0, (size_t)N * 4, stream);
    hipMemsetAsync(cursor, 0, (size_t)N * 4, stream);
    count_kernel<<<(E + 255) / 256, 256, 0, stream>>>(ei, deg, E);
    const int nb = (N + 1023) / 1024;
    scan_local<<<nb, 1024, 0, stream>>>(deg, row_start, bsum, N);
    scan_bsums<<<1, 64, 0, stream>>>(bsum, nb);
    scan_add<<<nb, 1024, 0, stream>>>(row_start, bsum, N);
    fill_kernel<<<(E + 255) / 256, 256, 0, stream>>>(ei, row_start, cursor, csr_eid, csr_j, E);
    rbf_csr_kernel<<<(E + 255) / 256, 256, 0, stream>>>(csr_eid, ei, pos, freqs, rbf_csr, E);

    // ---- init: embed + fc0 (2 gelu layers) ----
    const int GF = 256;  // 1 persistent block per CU (launch_bounds(512,2) => 1 block/CU)
    fc0_fused<<<GF, 512, 0, stream>>>(z, emb_table, emb_W, emb_b, fc0t, fc0t + 65536, fc0_b,
                                      fc0_b + 256, x, xb, N);

    // ---- interaction blocks ----
    for (int n = 0; n < 4; ++n) {
        gemm_rb<256, 64><<<1024, 256, 0, stream>>>(xb, wvt + n * 16384, vb, N);
        msg_kernel<<<(N + 3) / 4, 256, 0, stream>>>(row_start, csr_j, rbf_csr, vb,
                                                    conv_Wrbf + n * RR * MM, aggb, N, E);
        block_fused<<<GF, 512, 0, stream>>>(aggb, x, xb, wott + n * 16384, fct + (n * 2) * 65536,
                                            fct + (n * 2 + 1) * 65536, fc_b + n * 2 * 256,
                                            fc_b + (n * 2 + 1) * 256, N);
    }
}

// Round 8
// 747.835 us; speedup vs baseline: 1.6814x; 1.2544x over previous
//
#include <hip/hip_runtime.h>
#include <hip/hip_bf16.h>

typedef __bf16 bf16_t;
typedef bf16_t bf16x8 __attribute__((ext_vector_type(8)));
typedef bf16_t bf16x4 __attribute__((ext_vector_type(4)));
typedef float f32x4 __attribute__((ext_vector_type(4)));

#define DD 256
#define MM 64
#define RR 12

__device__ __forceinline__ float gelu_fast(float x) {
    // tanh-approx gelu via exp identity: tanh(u) = sign(u)*(1-e^{-2|u|})/(1+e^{-2|u|})
    float u = x * (0.7978845608f + 0.0356774081f * x * x);
    float t = __expf(-2.f * fabsf(u));
    float th = (1.f - t) / (1.f + t);
    th = copysignf(th, u);
    return 0.5f * x * (1.f + th);
}

__device__ __forceinline__ bf16x8 zero8() {
    bf16x8 z;
#pragma unroll
    for (int i = 0; i < 8; ++i) z[i] = (bf16_t)0.f;
    return z;
}

// ---------- weight prep: fp32 [K][C] -> bf16 transposed [C][K], batched over blockIdx.y ----------
__global__ void cvt_transpose_kernel(const float* __restrict__ src, bf16_t* __restrict__ dst,
                                     int K, int C) {
    int m = blockIdx.y;
    const float* s = src + (size_t)m * K * C;
    bf16_t* d = dst + (size_t)m * K * C;
    int idx = blockIdx.x * 256 + threadIdx.x;
    if (idx < K * C) {
        int k = idx / C, c = idx - k * C;
        d[c * K + k] = (bf16_t)s[idx];
    }
}

// ---------- register-B MFMA GEMM (used for Wv only) ----------
template <int K, int NCOL>
__global__ __launch_bounds__(256, 4) void gemm_rb(const bf16_t* __restrict__ A,
                                                  const bf16_t* __restrict__ Wt,
                                                  bf16_t* __restrict__ Cb, int M) {
    constexpr int NSTEP = K / 32;
    constexpr int NF = NCOL / 64;
    const int t = threadIdx.x;
    const int wave = t >> 6, lane = t & 63;
    const int l15 = lane & 15, lhi = lane >> 4;
    const int colbase = wave * (NCOL / 4);

    bf16x8 bfr[NSTEP][NF];
#pragma unroll
    for (int ks = 0; ks < NSTEP; ++ks)
#pragma unroll
        for (int nf = 0; nf < NF; ++nf)
            bfr[ks][nf] =
                *(const bf16x8*)(Wt + (size_t)(colbase + nf * 16 + l15) * K + ks * 32 + lhi * 8);

    const bf16x8 z8 = zero8();
    for (int row0 = blockIdx.x * 32; row0 < M; row0 += gridDim.x * 32) {
        const int r0 = row0 + l15, r1 = row0 + 16 + l15;
        const bool g0 = r0 < M, g1 = r1 < M;
        const bf16_t* a0p = A + (size_t)r0 * K + lhi * 8;
        const bf16_t* a1p = A + (size_t)r1 * K + lhi * 8;

        f32x4 acc[2][NF];
#pragma unroll
        for (int mf = 0; mf < 2; ++mf)
#pragma unroll
            for (int nf = 0; nf < NF; ++nf) acc[mf][nf] = (f32x4){0.f, 0.f, 0.f, 0.f};

        bf16x8 a0 = g0 ? *(const bf16x8*)a0p : z8;
        bf16x8 a1 = g1 ? *(const bf16x8*)a1p : z8;
#pragma unroll
        for (int ks = 0; ks < NSTEP; ++ks) {
            bf16x8 n0 = z8, n1 = z8;
            if (ks + 1 < NSTEP) {
                n0 = g0 ? *(const bf16x8*)(a0p + (ks + 1) * 32) : z8;
                n1 = g1 ? *(const bf16x8*)(a1p + (ks + 1) * 32) : z8;
            }
#pragma unroll
            for (int nf = 0; nf < NF; ++nf)
                acc[0][nf] = __builtin_amdgcn_mfma_f32_16x16x32_bf16(a0, bfr[ks][nf], acc[0][nf], 0, 0, 0);
#pragma unroll
            for (int nf = 0; nf < NF; ++nf)
                acc[1][nf] = __builtin_amdgcn_mfma_f32_16x16x32_bf16(a1, bfr[ks][nf], acc[1][nf], 0, 0, 0);
            a0 = n0;
            a1 = n1;
        }
#pragma unroll
        for (int mf = 0; mf < 2; ++mf)
#pragma unroll
            for (int nf = 0; nf < NF; ++nf) {
                int col = colbase + nf * 16 + l15;
#pragma unroll
                for (int r = 0; r < 4; ++r) {
                    int row = row0 + mf * 16 + lhi * 4 + r;
                    if (row < M) Cb[(size_t)row * NCOL + col] = (bf16_t)acc[mf][nf][r];
                }
            }
    }
}

// ---------- fused interaction block: x = x + agg@Wout; x = x + gelu(gelu(x@W1+b1)@W2+b2) ----------
// 512 threads = 8 waves; wave owns 32 output cols; 32-row tiles; B in VGPRs; LDS for intermediates.
// Cross-tile register prefetch of aggb/x hides global latency under fc1+fc2 MFMA.
__global__ __launch_bounds__(512, 2) void block_fused(
    const bf16_t* __restrict__ aggb, float* __restrict__ x, bf16_t* __restrict__ xb,
    const bf16_t* __restrict__ woutt, const bf16_t* __restrict__ fc1t,
    const bf16_t* __restrict__ fc2t, const float* __restrict__ b1, const float* __restrict__ b2,
    int M) {
    __shared__ bf16_t lds1[32][264];
    __shared__ bf16_t lds2[32][264];
    const int t = threadIdx.x, wave = t >> 6, lane = t & 63;
    const int l15 = lane & 15, lhi = lane >> 4;
    const int cb = wave * 32;
    const int STRIDE = gridDim.x * 32;

    bf16x8 bw[2][2], br1[8][2], br2[8][2];
#pragma unroll
    for (int ks = 0; ks < 2; ++ks)
#pragma unroll
        for (int nf = 0; nf < 2; ++nf)
            bw[ks][nf] = *(const bf16x8*)(woutt + (size_t)(cb + nf * 16 + l15) * 64 + ks * 32 + lhi * 8);
#pragma unroll
    for (int ks = 0; ks < 8; ++ks)
#pragma unroll
        for (int nf = 0; nf < 2; ++nf) {
            br1[ks][nf] = *(const bf16x8*)(fc1t + (size_t)(cb + nf * 16 + l15) * 256 + ks * 32 + lhi * 8);
            br2[ks][nf] = *(const bf16x8*)(fc2t + (size_t)(cb + nf * 16 + l15) * 256 + ks * 32 + lhi * 8);
        }
    float bias1[2], bias2[2];
#pragma unroll
    for (int nf = 0; nf < 2; ++nf) {
        bias1[nf] = b1[cb + nf * 16 + l15];
        bias2[nf] = b2[cb + nf * 16 + l15];
    }

    const bf16x8 z8 = zero8();
    bf16x8 pfa[2][2];
    float pfx[2][2][4];
    auto PREFETCH = [&](int r0) {
        const int rr0 = r0 + l15, rr1 = r0 + 16 + l15;
#pragma unroll
        for (int ks = 0; ks < 2; ++ks) {
            pfa[0][ks] = (rr0 < M) ? *(const bf16x8*)(aggb + (size_t)rr0 * 64 + ks * 32 + lhi * 8) : z8;
            pfa[1][ks] = (rr1 < M) ? *(const bf16x8*)(aggb + (size_t)rr1 * 64 + ks * 32 + lhi * 8) : z8;
        }
#pragma unroll
        for (int mf = 0; mf < 2; ++mf)
#pragma unroll
            for (int nf = 0; nf < 2; ++nf)
#pragma unroll
                for (int r = 0; r < 4; ++r) {
                    int row = r0 + mf * 16 + lhi * 4 + r;
                    pfx[mf][nf][r] = (row < M) ? x[(size_t)row * 256 + cb + nf * 16 + l15] : 0.f;
                }
    };

    PREFETCH(blockIdx.x * 32);
    for (int row0 = blockIdx.x * 32; row0 < M; row0 += STRIDE) {
        // ---- phase A: h = agg@Wout + x (all operands already in registers) ----
        f32x4 h[2][2];
#pragma unroll
        for (int mf = 0; mf < 2; ++mf)
#pragma unroll
            for (int nf = 0; nf < 2; ++nf) h[mf][nf] = (f32x4){0.f, 0.f, 0.f, 0.f};
#pragma unroll
        for (int ks = 0; ks < 2; ++ks)
#pragma unroll
            for (int nf = 0; nf < 2; ++nf) {
                h[0][nf] = __builtin_amdgcn_mfma_f32_16x16x32_bf16(pfa[0][ks], bw[ks][nf], h[0][nf], 0, 0, 0);
                h[1][nf] = __builtin_amdgcn_mfma_f32_16x16x32_bf16(pfa[1][ks], bw[ks][nf], h[1][nf], 0, 0, 0);
            }
#pragma unroll
        for (int mf = 0; mf < 2; ++mf)
#pragma unroll
            for (int nf = 0; nf < 2; ++nf) {
                int col = cb + nf * 16 + l15;
#pragma unroll
                for (int r = 0; r < 4; ++r) {
                    int lrow = mf * 16 + lhi * 4 + r;
                    float hv = h[mf][nf][r] + pfx[mf][nf][r];
                    h[mf][nf][r] = hv;
                    lds1[lrow][col] = (bf16_t)hv;
                }
            }
        __syncthreads();  // B1
        if (row0 + STRIDE < M) PREFETCH(row0 + STRIDE);  // lands under fc1+fc2 MFMA
        // ---- fc1 ----
        f32x4 acc[2][2];
#pragma unroll
        for (int mf = 0; mf < 2; ++mf)
#pragma unroll
            for (int nf = 0; nf < 2; ++nf) acc[mf][nf] = (f32x4){0.f, 0.f, 0.f, 0.f};
#pragma unroll
        for (int ks = 0; ks < 8; ++ks) {
            bf16x8 a0 = *(const bf16x8*)&lds1[l15][ks * 32 + lhi * 8];
            bf16x8 a1 = *(const bf16x8*)&lds1[16 + l15][ks * 32 + lhi * 8];
#pragma unroll
            for (int nf = 0; nf < 2; ++nf) {
                acc[0][nf] = __builtin_amdgcn_mfma_f32_16x16x32_bf16(a0, br1[ks][nf], acc[0][nf], 0, 0, 0);
                acc[1][nf] = __builtin_amdgcn_mfma_f32_16x16x32_bf16(a1, br1[ks][nf], acc[1][nf], 0, 0, 0);
            }
        }
#pragma unroll
        for (int mf = 0; mf < 2; ++mf)
#pragma unroll
            for (int nf = 0; nf < 2; ++nf) {
                int col = cb + nf * 16 + l15;
#pragma unroll
                for (int r = 0; r < 4; ++r)
                    lds2[mf * 16 + lhi * 4 + r][col] = (bf16_t)gelu_fast(acc[mf][nf][r] + bias1[nf]);
            }
        __syncthreads();  // B2
        // ---- fc2 + residual epilogue ----
#pragma unroll
        for (int mf = 0; mf < 2; ++mf)
#pragma unroll
            for (int nf = 0; nf < 2; ++nf) acc[mf][nf] = (f32x4){0.f, 0.f, 0.f, 0.f};
#pragma unroll
        for (int ks = 0; ks < 8; ++ks) {
            bf16x8 a0 = *(const bf16x8*)&lds2[l15][ks * 32 + lhi * 8];
            bf16x8 a1 = *(const bf16x8*)&lds2[16 + l15][ks * 32 + lhi * 8];
#pragma unroll
            for (int nf = 0; nf < 2; ++nf) {
                acc[0][nf] = __builtin_amdgcn_mfma_f32_16x16x32_bf16(a0, br2[ks][nf], acc[0][nf], 0, 0, 0);
                acc[1][nf] = __builtin_amdgcn_mfma_f32_16x16x32_bf16(a1, br2[ks][nf], acc[1][nf], 0, 0, 0);
            }
        }
#pragma unroll
        for (int mf = 0; mf < 2; ++mf)
#pragma unroll
            for (int nf = 0; nf < 2; ++nf) {
                int col = cb + nf * 16 + l15;
#pragma unroll
                for (int r = 0; r < 4; ++r) {
                    int row = row0 + mf * 16 + lhi * 4 + r;
                    if (row < M) {
                        float o = h[mf][nf][r] + gelu_fast(acc[mf][nf][r] + bias2[nf]);
                        x[(size_t)row * 256 + col] = o;
                        xb[(size_t)row * 256 + col] = (bf16_t)o;
                    }
                }
            }
        // no trailing barrier: next-tile lds1 writes are ordered by next B1/B2 (round-4 proof)
    }
}

// ---------- fused init: embed -> fc0.1 -> fc0.2 (no residual) ----------
__global__ __launch_bounds__(512, 2) void fc0_fused(
    const int* __restrict__ z, const float* __restrict__ table, const float* __restrict__ embW,
    const float* __restrict__ embb, const bf16_t* __restrict__ fc1t,
    const bf16_t* __restrict__ fc2t, const float* __restrict__ b1, const float* __restrict__ b2,
    float* __restrict__ x, bf16_t* __restrict__ xb, int M) {
    __shared__ bf16_t lds1[32][264];
    __shared__ bf16_t lds2[32][264];
    const int t = threadIdx.x, wave = t >> 6, lane = t & 63;
    const int l15 = lane & 15, lhi = lane >> 4;
    const int cb = wave * 32;
    const int erow = t >> 4, ecol0 = (t & 15) * 16;

    bf16x8 br1[8][2], br2[8][2];
#pragma unroll
    for (int ks = 0; ks < 8; ++ks)
#pragma unroll
        for (int nf = 0; nf < 2; ++nf) {
            br1[ks][nf] = *(const bf16x8*)(fc1t + (size_t)(cb + nf * 16 + l15) * 256 + ks * 32 + lhi * 8);
            br2[ks][nf] = *(const bf16x8*)(fc2t + (size_t)(cb + nf * 16 + l15) * 256 + ks * 32 + lhi * 8);
        }
    float bias1[2], bias2[2];
#pragma unroll
    for (int nf = 0; nf < 2; ++nf) {
        bias1[nf] = b1[cb + nf * 16 + l15];
        bias2[nf] = b2[cb + nf * 16 + l15];
    }

    for (int row0 = blockIdx.x * 32; row0 < M; row0 += gridDim.x * 32) {
        // ---- embed into lds1 ----
        int grow = row0 + erow;
        if (grow < M) {
            int zi = z[grow];
            float tr[5];
#pragma unroll
            for (int hh = 0; hh < 5; ++hh) tr[hh] = table[zi * 5 + hh];
#pragma unroll
            for (int c = 0; c < 16; ++c) {
                int col = ecol0 + c;
                float a = embb[col];
#pragma unroll
                for (int hh = 0; hh < 5; ++hh) a += tr[hh] * embW[hh * 256 + col];
                lds1[erow][col] = (bf16_t)a;
            }
        } else {
#pragma unroll
            for (int c = 0; c < 16; ++c) lds1[erow][ecol0 + c] = (bf16_t)0.f;
        }
        __syncthreads();
        // ---- fc0.1 ----
        f32x4 acc[2][2];
#pragma unroll
        for (int mf = 0; mf < 2; ++mf)
#pragma unroll
            for (int nf = 0; nf < 2; ++nf) acc[mf][nf] = (f32x4){0.f, 0.f, 0.f, 0.f};
#pragma unroll
        for (int ks = 0; ks < 8; ++ks) {
            bf16x8 a0 = *(const bf16x8*)&lds1[l15][ks * 32 + lhi * 8];
            bf16x8 a1 = *(const bf16x8*)&lds1[16 + l15][ks * 32 + lhi * 8];
#pragma unroll
            for (int nf = 0; nf < 2; ++nf) {
                acc[0][nf] = __builtin_amdgcn_mfma_f32_16x16x32_bf16(a0, br1[ks][nf], acc[0][nf], 0, 0, 0);
                acc[1][nf] = __builtin_amdgcn_mfma_f32_16x16x32_bf16(a1, br1[ks][nf], acc[1][nf], 0, 0, 0);
            }
        }
#pragma unroll
        for (int mf = 0; mf < 2; ++mf)
#pragma unroll
            for (int nf = 0; nf < 2; ++nf) {
                int col = cb + nf * 16 + l15;
#pragma unroll
                for (int r = 0; r < 4; ++r)
                    lds2[mf * 16 + lhi * 4 + r][col] = (bf16_t)gelu_fast(acc[mf][nf][r] + bias1[nf]);
            }
        __syncthreads();
        // ---- fc0.2 ----
#pragma unroll
        for (int mf = 0; mf < 2; ++mf)
#pragma unroll
            for (int nf = 0; nf < 2; ++nf) acc[mf][nf] = (f32x4){0.f, 0.f, 0.f, 0.f};
#pragma unroll
        for (int ks = 0; ks < 8; ++ks) {
            bf16x8 a0 = *(const bf16x8*)&lds2[l15][ks * 32 + lhi * 8];
            bf16x8 a1 = *(const bf16x8*)&lds2[16 + l15][ks * 32 + lhi * 8];
#pragma unroll
            for (int nf = 0; nf < 2; ++nf) {
                acc[0][nf] = __builtin_amdgcn_mfma_f32_16x16x32_bf16(a0, br2[ks][nf], acc[0][nf], 0, 0, 0);
                acc[1][nf] = __builtin_amdgcn_mfma_f32_16x16x32_bf16(a1, br2[ks][nf], acc[1][nf], 0, 0, 0);
            }
        }
#pragma unroll
        for (int mf = 0; mf < 2; ++mf)
#pragma unroll
            for (int nf = 0; nf < 2; ++nf) {
                int col = cb + nf * 16 + l15;
#pragma unroll
                for (int r = 0; r < 4; ++r) {
                    int row = row0 + mf * 16 + lhi * 4 + r;
                    if (row < M) {
                        float o = gelu_fast(acc[mf][nf][r] + bias2[nf]);
                        x[(size_t)row * 256 + col] = o;
                        xb[(size_t)row * 256 + col] = (bf16_t)o;
                    }
                }
            }
    }
}

// ---------- CSR build ----------
__global__ void count_kernel(const int* __restrict__ ei, int* __restrict__ deg, int E) {
    int e = blockIdx.x * 256 + threadIdx.x;
    if (e < E) atomicAdd(&deg[ei[e]], 1);
}

__global__ void scan_local(const int* __restrict__ deg, int* __restrict__ rs,
                           int* __restrict__ bsum, int N) {
    __shared__ int sd[1024];
    int t = threadIdx.x, i = blockIdx.x * 1024 + t;
    int val = (i < N) ? deg[i] : 0;
    sd[t] = val;
    __syncthreads();
    for (int off = 1; off < 1024; off <<= 1) {
        int tv = (t >= off) ? sd[t - off] : 0;
        __syncthreads();
        sd[t] += tv;
        __syncthreads();
    }
    if (i < N) rs[i] = sd[t] - val;
    if (t == 1023) bsum[blockIdx.x] = sd[1023];
}

__global__ void scan_bsums(int* __restrict__ bsum, int nb) {
    if (threadIdx.x == 0) {
        int run = 0;
        for (int b = 0; b < nb; ++b) {
            int v = bsum[b];
            bsum[b] = run;
            run += v;
        }
        bsum[nb] = run;
    }
}

__global__ void scan_add(int* __restrict__ rs, const int* __restrict__ bsum, int N) {
    int i = blockIdx.x * 1024 + threadIdx.x;
    if (i < N) rs[i] += bsum[blockIdx.x];
    if (i == 0) rs[N] = bsum[gridDim.x];
}

__global__ void fill_kernel(const int* __restrict__ ei, const int* __restrict__ row_start,
                            int* __restrict__ cursor, int* __restrict__ csr_eid,
                            int* __restrict__ csr_j, int E) {
    int e = blockIdx.x * 256 + threadIdx.x;
    if (e < E) {
        int i = ei[e];
        int p = atomicAdd(&cursor[i], 1);
        int o = row_start[i] + p;
        csr_eid[o] = e;
        csr_j[o] = ei[E + e];
    }
}

// ---------- rbf in CSR order (bf16, rows padded to 16 elems / 32B, pad zeroed) ----------
__global__ void rbf_csr_kernel(const int* __restrict__ csr_eid, const int* __restrict__ ei,
                               const float* __restrict__ pos, const float* __restrict__ freqs,
                               bf16_t* __restrict__ rbf_csr, int E) {
    int idx = blockIdx.x * 256 + threadIdx.x;
    if (idx >= E) return;
    int e = csr_eid[idx];
    int i = ei[e], j = ei[E + e];
    float dx = pos[i * 3 + 0] - pos[j * 3 + 0];
    float dy = pos[i * 3 + 1] - pos[j * 3 + 1];
    float dz = pos[i * 3 + 2] - pos[j * 3 + 2];
    float dist = sqrtf(dx * dx + dy * dy + dz * dz + 1e-12f);
    float x = dist * 0.2f;
    float x4 = (x * x) * (x * x);
    float env = 1.0f / x + x4 * (-21.0f + x * (35.0f - 15.0f * x));
    bf16x8 lo, hi;
#pragma unroll
    for (int r = 0; r < 8; ++r) lo[r] = (bf16_t)(env * sinf(freqs[r] * x));
#pragma unroll
    for (int r = 0; r < 4; ++r) hi[r] = (bf16_t)(env * sinf(freqs[8 + r] * x));
#pragma unroll
    for (int r = 4; r < 8; ++r) hi[r] = (bf16_t)0.f;
    bf16_t* dst = rbf_csr + (size_t)idx * 16;
    *(bf16x8*)dst = lo;
    *(bf16x8*)(dst + 8) = hi;
}

// ---------- message gather: persistent waves, MFMA gate, Wrbf prologue amortized ----------
__global__ __launch_bounds__(256) void msg_kernel(const int* __restrict__ row_start,
                                                  const int* __restrict__ csr_j,
                                                  const bf16_t* __restrict__ rbf_csr,
                                                  const bf16_t* __restrict__ v,
                                                  const float* __restrict__ Wrbf,
                                                  bf16_t* __restrict__ agg, int N, int E) {
    const int wave = threadIdx.x >> 6, lane = threadIdx.x & 63;
    const int l15 = lane & 15, lhi = lane >> 4;
    // hoisted prologue: Wrbf fragments (dim = l15*4+nf, k = lhi*8+j)
    bf16x8 wrb[4];
#pragma unroll
    for (int nf = 0; nf < 4; ++nf) {
#pragma unroll
        for (int j = 0; j < 8; ++j) {
            int k = lhi * 8 + j;
            wrb[nf][j] = (k < 12) ? (bf16_t)Wrbf[k * 64 + l15 * 4 + nf] : (bf16_t)0.f;
        }
    }
    const bf16x8 z8 = zero8();
    const int NSTRIDE = gridDim.x * 4;
    for (int nd = blockIdx.x * 4 + wave; nd < N; nd += NSTRIDE) {
        const int s = row_start[nd], e = row_start[nd + 1];
        float acc[4] = {0.f, 0.f, 0.f, 0.f};
        for (int g0 = s; g0 < e; g0 += 16) {
            int ea = g0 + l15;
            bf16x8 af = (lhi < 2 && ea < e) ? *(const bf16x8*)(rbf_csr + (size_t)ea * 16 + lhi * 8) : z8;
            f32x4 gacc[4];
#pragma unroll
            for (int nf = 0; nf < 4; ++nf)
                gacc[nf] = __builtin_amdgcn_mfma_f32_16x16x32_bf16(af, wrb[nf],
                                                                   (f32x4){0.f, 0.f, 0.f, 0.f}, 0, 0, 0);
#pragma unroll
            for (int r = 0; r < 4; ++r) {
                int er = g0 + lhi * 4 + r;
                int jj = csr_j[er < e ? er : s];
                bf16x4 vj = *(const bf16x4*)(v + (size_t)jj * 64 + l15 * 4);
                bool valid = er < e;
#pragma unroll
                for (int nf = 0; nf < 4; ++nf) acc[nf] += valid ? gacc[nf][r] * (float)vj[nf] : 0.f;
            }
        }
#pragma unroll
        for (int nf = 0; nf < 4; ++nf) {
            acc[nf] += __shfl_xor(acc[nf], 16, 64);
            acc[nf] += __shfl_xor(acc[nf], 32, 64);
        }
        if (lhi == 0) {
            bf16x4 o;
#pragma unroll
            for (int nf = 0; nf < 4; ++nf) o[nf] = (bf16_t)acc[nf];
            *(bf16x4*)(agg + (size_t)nd * 64 + l15 * 4) = o;
        }
    }
}

extern "C" void kernel_launch(void* const* d_in, const int* in_sizes, int n_in, void* d_out,
                              int out_size, void* d_ws, size_t ws_size, hipStream_t stream) {
    const int* z = (const int*)d_in[0];
    const float* pos = (const float*)d_in[1];
    const int* ei = (const int*)d_in[4];
    const float* emb_table = (const float*)d_in[5];
    const float* emb_W = (const float*)d_in[6];
    const float* emb_b = (const float*)d_in[7];
    const float* freqs = (const float*)d_in[8];
    const float* fc0_W = (const float*)d_in[9];
    const float* fc0_b = (const float*)d_in[10];
    const float* conv_Wv = (const float*)d_in[11];
    const float* conv_Wrbf = (const float*)d_in[12];
    const float* conv_Wout = (const float*)d_in[13];
    const float* fc_W = (const float*)d_in[14];
    const float* fc_b = (const float*)d_in[15];
    float* x = (float*)d_out;

    const int N = in_sizes[0];
    const int E = in_sizes[4] / 2;

    // ---- workspace carve ----
    char* wsp = (char*)d_ws;
    auto alloc = [&](size_t bytes) {
        void* p = (void*)wsp;
        wsp += (bytes + 255) & ~(size_t)255;
        return p;
    };
    bf16_t* xb = (bf16_t*)alloc((size_t)N * DD * 2);
    bf16_t* vb = (bf16_t*)alloc((size_t)N * MM * 2);
    bf16_t* aggb = (bf16_t*)alloc((size_t)N * MM * 2);
    bf16_t* rbf_csr = (bf16_t*)alloc((size_t)E * 16 * 2);
    int* deg = (int*)alloc((size_t)N * 4);
    int* cursor = (int*)alloc((size_t)N * 4);
    int* row_start = (int*)alloc((size_t)(N + 1) * 4);
    int* bsum = (int*)alloc((size_t)256 * 4);
    int* csr_eid = (int*)alloc((size_t)E * 4);
    int* csr_j = (int*)alloc((size_t)E * 4);
    bf16_t* wbf = (bf16_t*)alloc((size_t)786432 * 2);
    bf16_t* fc0t = wbf;              // 2 x [256][256]
    bf16_t* fct = wbf + 2 * 65536;   // 8 x [256][256]
    bf16_t* wvt = wbf + 10 * 65536;  // 4 x [64 cols][256 k]
    bf16_t* wott = wvt + 4 * 16384;  // 4 x [256 cols][64 k]

    // ---- weight prep ----
    cvt_transpose_kernel<<<dim3(256, 2), 256, 0, stream>>>(fc0_W, fc0t, 256, 256);
    cvt_transpose_kernel<<<dim3(256, 8), 256, 0, stream>>>(fc_W, fct, 256, 256);
    cvt_transpose_kernel<<<dim3(64, 4), 256, 0, stream>>>(conv_Wv, wvt, 256, 64);
    cvt_transpose_kernel<<<dim3(64, 4), 256, 0, stream>>>(conv_Wout, wott, 64, 256);

    // ---- CSR by destination, rbf in CSR order ----
    hipMemsetAsync(deg, 0, (size_t)N * 4, stream);
    hipMemsetAsync(cursor, 0, (size_t)N * 4, stream);
    count_kernel<<<(E + 255) / 256, 256, 0, stream>>>(ei, deg, E);
    const int nb = (N + 1023) / 1024;
    scan_local<<<nb, 1024, 0, stream>>>(deg, row_start, bsum, N);
    scan_bsums<<<1, 64, 0, stream>>>(bsum, nb);
    scan_add<<<nb, 1024, 0, stream>>>(row_start, bsum, N);
    fill_kernel<<<(E + 255) / 256, 256, 0, stream>>>(ei, row_start, cursor, csr_eid, csr_j, E);
    rbf_csr_kernel<<<(E + 255) / 256, 256, 0, stream>>>(csr_eid, ei, pos, freqs, rbf_csr, E);

    // ---- init: embed + fc0 (2 gelu layers) ----
    const int GF = 256;  // 1 persistent block per CU (launch_bounds(512,2) => 1 block/CU)
    fc0_fused<<<GF, 512, 0, stream>>>(z, emb_table, emb_W, emb_b, fc0t, fc0t + 65536, fc0_b,
                                      fc0_b + 256, x, xb, N);

    // ---- interaction blocks ----
    for (int n = 0; n < 4; ++n) {
        gemm_rb<256, 64><<<1024, 256, 0, stream>>>(xb, wvt + n * 16384, vb, N);
        msg_kernel<<<2048, 256, 0, stream>>>(row_start, csr_j, rbf_csr, vb,
                                             conv_Wrbf + n * RR * MM, aggb, N, E);
        block_fused<<<GF, 512, 0, stream>>>(aggb, x, xb, wott + n * 16384, fct + (n * 2) * 65536,
                                            fct + (n * 2 + 1) * 65536, fc_b + n * 2 * 256,
                                            fc_b + (n * 2 + 1) * 256, N);
    }
}